// Round 11
// baseline (69.737 us; speedup 1.0000x reference)
//
#include <hip/hip_runtime.h>
#include <math.h>

#define CC 128   // channels
#define NN 1024  // H*W
#define BTOT 32  // B*T
#define CP 152   // k_front LDS row stride (bf16 elems)
#define CQS 36   // conv_q row stride (f32): 144B = 9*16

typedef unsigned short u16;
typedef u16 u16x8 __attribute__((ext_vector_type(8)));
typedef u16 u16x4 __attribute__((ext_vector_type(4)));
typedef __bf16 bf16x8 __attribute__((ext_vector_type(8)));
typedef float f32x4 __attribute__((ext_vector_type(4)));

__device__ __forceinline__ u16 f2b(float f) {
    unsigned int u = __float_as_uint(f);
    u += 0x7FFFu + ((u >> 16) & 1u);   // RNE
    return (u16)(u >> 16);
}
__device__ __forceinline__ float b2f(u16 u) {
    return __uint_as_float(((unsigned int)u) << 16);
}

// ---------- MFMA helpers ----------
// A-frag: lane l holds A[16*ot + (l&15)][32*kk + 8*(l>>4) + j], j=0..7.
// B-frag: lane l holds B[16*nt + (l&15)][32*kk + 8*(l>>4) + j].
// C/D: col = l&15 (B row), row = (l>>4)*4 + r (+16*ot) (A row).
// k-slot permutations (A/B must agree; logical order is free):
//  sigma (vN spatial): slot(ky): q=ky>>2,r=ky&3 -> q<4 ? 8q+r : 8(q-4)+4+r
//  pi2   (Wf columns): c(32kk+8g+j) = 32kk + 16*(j>=4) + 4g + (j&3)
__device__ __forceinline__ void loadB(const u16* brow, int g, bf16x8 bfr[4]) {
#pragma unroll
    for (int kk = 0; kk < 4; ++kk)
        bfr[kk] = *(const bf16x8*)(brow + kk * 32 + g * 8);
}
__device__ __forceinline__ bf16x8 ldA(const u16* __restrict__ WB, int ot, int kk, int l) {
    return *(const bf16x8*)(WB + ((size_t)(ot * 4 + kk) * 64 + l) * 8);
}

// ---------- kernel 0: prep — pack We/Wd/Wf AND compose+pack Wqe/Wkd/Wvd ----------
__global__ __launch_bounds__(256) void k_prep(
    const float* __restrict__ We, const float* __restrict__ Wd,
    const float* __restrict__ Wf, const float* __restrict__ Wq,
    const float* __restrict__ Wk, const float* __restrict__ Wv,
    const float* __restrict__ be, const float* __restrict__ bd,
    u16* __restrict__ out, float* __restrict__ cvec)
{
    const int bid = blockIdx.x, t = threadIdx.x;
    if (bid < 24) {
        // plain pack: We->slot0, Wd->slot1, Wf->slot5 (Wf with pi2 column perm)
        const int gid = bid * 256 + t;       // 0..6143
        const int wi = gid >> 11;            // 0..2
        const float* W = (wi == 0) ? We : (wi == 1) ? Wd : Wf;
        const int slot = (wi == 2) ? 5 : wi;
        const int rem = gid & 2047;
        const int ot = rem >> 8, kk = (rem >> 6) & 3, l = rem & 63;
        const int row = ot * 16 + (l & 15);
        int colA, colB;
        if (wi == 2) { colA = kk * 32 + (l >> 4) * 4; colB = colA + 16; }  // pi2
        else         { colA = kk * 32 + (l >> 4) * 8; colB = colA + 4; }
        float4 a = *(const float4*)(W + row * CC + colA);
        float4 b = *(const float4*)(W + row * CC + colB);
        u16x8 u;
        u[0] = f2b(a.x); u[1] = f2b(a.y); u[2] = f2b(a.z); u[3] = f2b(a.w);
        u[4] = f2b(b.x); u[5] = f2b(b.y); u[6] = f2b(b.z); u[7] = f2b(b.w);
        *(u16x8*)(out + (size_t)slot * 16384 + ((size_t)(ot * 4 + kk) * 64 + l) * 8) = u;
    } else {
        // compose: Wqe=Wq*We (slot2), Wkd=Wk*Wd (slot3), Wvd=Wv*Wd (slot4)
        const int cid = bid - 24;            // 0..191
        const int mat = cid >> 6;            // 0..2
        const int o = ((cid & 63) << 1) | (t >> 7);
        const int c = t & 127;
        const float* A = (mat == 0) ? Wq : (mat == 1) ? Wk : Wv;
        const float* B = (mat == 0) ? We : Wd;
        const float* bvec = (mat == 0) ? be : bd;
        float acc = 0.f;
        for (int m = 0; m < CC; ++m) acc += A[o * CC + m] * B[m * CC + c];
        const int ot = o >> 4, l15o = o & 15;
        const int kk = c >> 5, gc = (c >> 3) & 3, j = c & 7;
        const int l = gc * 16 + l15o;
        out[(size_t)(2 + mat) * 16384 + ((size_t)(ot * 4 + kk) * 64 + l) * 8 + j] = f2b(acc);
        if (c == 0) {
            float bacc = 0.f;
            for (int m = 0; m < CC; ++m) bacc += A[o * CC + m] * bvec[m];
            cvec[mat * CC + o] = bacc;
        }
    }
}

// ---------- kernel 1: front — 64-n tiles, XCD-aligned grid ----------
// 1D grid of 512: bt = (id&7)*4 + ((id>>3)&3), tile = id>>5.
// Emits eexp = exp(l2e) + per-block partial sums (replaces k_dens).
// vN stored with sigma-permuted spatial order within each 32-tile.
__global__ __launch_bounds__(256) void k_front(
    const float* __restrict__ edge, const float* __restrict__ dvs,
    const u16* __restrict__ WeB, const u16* __restrict__ WdB,
    const u16* __restrict__ WqeB, const u16* __restrict__ WkdB,
    const u16* __restrict__ WvdB,
    const float* __restrict__ be, const float* __restrict__ bd,
    const float* __restrict__ bq,
    const float* __restrict__ cq, const float* __restrict__ ck,
    const float* __restrict__ cv,
    float* __restrict__ eexp_out, float* __restrict__ partial,
    u16* __restrict__ qT, u16* __restrict__ kT, u16* __restrict__ vN)
{
    __shared__ u16 bufA[64 * CP];
    __shared__ u16 bufB[64 * CP];
    __shared__ float redp[4];
    const int t = threadIdx.x;
    const int id = blockIdx.x;
    const int bt = (id & 7) * 4 + ((id >> 3) & 3);
    const int n0b = (id >> 5) * 64;
    const float* eb = edge + (size_t)bt * CC * NN + n0b;
    const float* db = dvs + (size_t)bt * CC * NN + n0b;

    // stage: transpose [c][n] fp32 -> [n][c] bf16
#pragma unroll
    for (int j = 0; j < 2; ++j) {
        const int i = t + 256 * j;
        const int c4 = i >> 4, p = i & 15;
        float4 e[4], d[4];
#pragma unroll
        for (int m = 0; m < 4; ++m) {
            e[m] = *(const float4*)(eb + (size_t)(4 * c4 + m) * NN + 4 * p);
            d[m] = *(const float4*)(db + (size_t)(4 * c4 + m) * NN + 4 * p);
        }
#pragma unroll
        for (int n = 0; n < 4; ++n) {
            u16x4 ue, ud;
            ue[0] = f2b(((const float*)&e[0])[n]); ud[0] = f2b(((const float*)&d[0])[n]);
            ue[1] = f2b(((const float*)&e[1])[n]); ud[1] = f2b(((const float*)&d[1])[n]);
            ue[2] = f2b(((const float*)&e[2])[n]); ud[2] = f2b(((const float*)&d[2])[n]);
            ue[3] = f2b(((const float*)&e[3])[n]); ud[3] = f2b(((const float*)&d[3])[n]);
            *(u16x4*)&bufA[(4 * p + n) * CP + 4 * c4] = ue;
            *(u16x4*)&bufB[(4 * p + n) * CP + 4 * c4] = ud;
        }
    }
    __syncthreads();

    const int w = t >> 6, l = t & 63;
    const int l15 = l & 15, g = l >> 4;
    const int nloc = w * 16 + l15;
    const size_t gn = (size_t)bt * NN + n0b + nloc;

    bf16x8 bfrE[4], bfrD[4];
    loadB(bufA + nloc * CP, g, bfrE);
    loadB(bufB + nloc * CP, g, bfrD);

    // --- ef/df accumulators (stats only, never materialized) ---
    f32x4 aE[8], aD[8];
#pragma unroll
    for (int ot = 0; ot < 8; ++ot) {
        aE[ot] = *(const f32x4*)(be + 16 * ot + 4 * g);
        aD[ot] = *(const f32x4*)(bd + 16 * ot + 4 * g);
    }
#pragma unroll
    for (int ot = 0; ot < 8; ++ot)
#pragma unroll
        for (int kk = 0; kk < 4; ++kk) {
            aE[ot] = __builtin_amdgcn_mfma_f32_16x16x32_bf16(ldA(WeB, ot, kk, l), bfrE[kk], aE[ot], 0, 0, 0);
            aD[ot] = __builtin_amdgcn_mfma_f32_16x16x32_bf16(ldA(WdB, ot, kk, l), bfrD[kk], aD[ot], 0, 0, 0);
        }
    float s2e = 0.f, s2d = 0.f, sed = 0.f;
#pragma unroll
    for (int ot = 0; ot < 8; ++ot)
#pragma unroll
        for (int r = 0; r < 4; ++r) {
            const float fe = aE[ot][r], fd = aD[ot][r];
            s2e += fe * fe; s2d += fd * fd; sed += fe * fd;
        }
    s2e += __shfl_xor(s2e, 16); s2e += __shfl_xor(s2e, 32);
    s2d += __shfl_xor(s2d, 16); s2d += __shfl_xor(s2d, 32);
    sed += __shfl_xor(sed, 16); sed += __shfl_xor(sed, 32);
    const float le = sqrtf(s2e), ld = sqrtf(s2d);
    const float sim = (sed / ((le + 1e-6f) * (ld + 1e-6f)) + 1.0f) * 0.5f;
    const float ee = __expf(le);
    if (g == 0) eexp_out[gn] = ee;
    {
        float s = ee;
        s += __shfl_xor(s, 1); s += __shfl_xor(s, 2);
        s += __shfl_xor(s, 4); s += __shfl_xor(s, 8);
        if (l == 0) redp[w] = s;
    }

    // --- q = sim*(Wqe*e + cq) + bq ---
    {
        f32x4 aQ[8];
#pragma unroll
        for (int ot = 0; ot < 8; ++ot) aQ[ot] = *(const f32x4*)(cq + 16 * ot + 4 * g);
#pragma unroll
        for (int ot = 0; ot < 8; ++ot)
#pragma unroll
            for (int kk = 0; kk < 4; ++kk)
                aQ[ot] = __builtin_amdgcn_mfma_f32_16x16x32_bf16(ldA(WqeB, ot, kk, l), bfrE[kk], aQ[ot], 0, 0, 0);
#pragma unroll
        for (int ot = 0; ot < 8; ++ot) {
            f32x4 b4 = *(const f32x4*)(bq + 16 * ot + 4 * g);
            u16x4 u;
#pragma unroll
            for (int r = 0; r < 4; ++r) u[r] = f2b(sim * aQ[ot][r] + b4[r]);
            *(u16x4*)(qT + gn * CC + 16 * ot + 4 * g) = u;
        }
    }
    // --- kraw = Wkd*d + ck ---
    {
        f32x4 aK[8];
#pragma unroll
        for (int ot = 0; ot < 8; ++ot) aK[ot] = *(const f32x4*)(ck + 16 * ot + 4 * g);
#pragma unroll
        for (int ot = 0; ot < 8; ++ot)
#pragma unroll
            for (int kk = 0; kk < 4; ++kk)
                aK[ot] = __builtin_amdgcn_mfma_f32_16x16x32_bf16(ldA(WkdB, ot, kk, l), bfrD[kk], aK[ot], 0, 0, 0);
#pragma unroll
        for (int ot = 0; ot < 8; ++ot) {
            u16x4 u;
#pragma unroll
            for (int r = 0; r < 4; ++r) u[r] = f2b(aK[ot][r]);
            *(u16x4*)(kT + gn * CC + 16 * ot + 4 * g) = u;
        }
    }
    // --- vraw = Wvd*d + cv ; channel-major vN[c][sigma(n)] via LDS transpose ---
    {
        f32x4 aV[8];
#pragma unroll
        for (int ot = 0; ot < 8; ++ot) aV[ot] = *(const f32x4*)(cv + 16 * ot + 4 * g);
#pragma unroll
        for (int ot = 0; ot < 8; ++ot)
#pragma unroll
            for (int kk = 0; kk < 4; ++kk)
                aV[ot] = __builtin_amdgcn_mfma_f32_16x16x32_bf16(ldA(WvdB, ot, kk, l), bfrD[kk], aV[ot], 0, 0, 0);
        __syncthreads();  // bufA reads (loadB) all done; redp written
        if (t == 0)
            partial[(size_t)bt * 16 + (id >> 5)] = redp[0] + redp[1] + redp[2] + redp[3];
        u16* bufT = bufA; // [128][72] u16 = 9216 <= 64*CP
        // sigma-permuted slot for this lane's n (per-thread constant):
        const int permn = (w >> 1) * 32 + 8 * (l15 >> 2) + (l15 & 3) + ((w & 1) ? 4 : 0);
#pragma unroll
        for (int ot = 0; ot < 8; ++ot)
#pragma unroll
            for (int r = 0; r < 4; ++r)
                bufT[(16 * ot + 4 * g + r) * 72 + permn] = f2b(aV[ot][r]);
        __syncthreads();
#pragma unroll
        for (int p = 0; p < 4; ++p) {
            const int idx = t + 256 * p;
            const int c = idx >> 3, n8 = (idx & 7) * 8;
            *(u16x8*)(vN + ((size_t)bt * CC + c) * NN + n0b + n8) =
                *(const u16x8*)&bufT[c * 72 + n8];
        }
    }
}

// ---------- kernel 2: FUSED attention + output conv + LIF (all in-register) ----------
// block = (b, qx); wave w = time step tt; bt = b*4+w.
// QK^T acc packs DIRECTLY into PV B-frag (sigma-permuted vN);
// O acc packs DIRECTLY into conv B-frag (pi2-permuted WfB). LDS = LIF exchange only.
__global__ __launch_bounds__(256) void k_attnf(
    const u16* __restrict__ qT, const u16* __restrict__ kT,
    const u16* __restrict__ vN, const float* __restrict__ eexp,
    const float* __restrict__ partial,
    const float* __restrict__ bk, const float* __restrict__ bv,
    const u16* __restrict__ WfB, const float* __restrict__ bf,
    float* __restrict__ out)
{
    __shared__ float convq[4 * 32 * CQS];  // 18432 B
    const int t = threadIdx.x;
    const int id = blockIdx.x;
    const int b = id & 7, qx = id >> 3;   // XCD x owns b = x (matches k_front)
    const int w = t >> 6;
    const int bt = b * 4 + w;
    const int l = t & 63, l15 = l & 15, g = l >> 4;
    const size_t btNN = (size_t)bt * NN;
    const float invsq = 0.08838834764831843f;  // 1/sqrt(128)

    // softmax denom for this bt (fixed order -> deterministic)
    float S = 0.f;
    {
        const float* pp = partial + (size_t)bt * 16;
#pragma unroll
        for (int i = 0; i < 16; ++i) S += pp[i];
    }
    const float dscale = 1024.0f / S;

    // q fragments
    u16x8 ql[2][4];
#pragma unroll
    for (int nt = 0; nt < 2; ++nt)
#pragma unroll
        for (int kk = 0; kk < 4; ++kk)
            ql[nt][kk] = *(const u16x8*)(qT + (btNN + qx * 32 + 16 * nt + l15) * CC + 32 * kk + 8 * g);

    // qbk[nt] = q[qy]·bk
    float qbk[2] = {0.f, 0.f};
#pragma unroll
    for (int kk = 0; kk < 4; ++kk) {
        f32x4 b0 = *(const f32x4*)(bk + 32 * kk + 8 * g);
        f32x4 b1 = *(const f32x4*)(bk + 32 * kk + 8 * g + 4);
#pragma unroll
        for (int nt = 0; nt < 2; ++nt)
#pragma unroll
            for (int j = 0; j < 4; ++j) {
                qbk[nt] += b2f(ql[nt][kk][j]) * b0[j];
                qbk[nt] += b2f(ql[nt][kk][4 + j]) * b1[j];
            }
    }
#pragma unroll
    for (int nt = 0; nt < 2; ++nt) {
        qbk[nt] += __shfl_xor(qbk[nt], 16);
        qbk[nt] += __shfl_xor(qbk[nt], 32);
    }

    // ---- QK^T -> in-register P' -> PV over the 7 kx columns (no LDS!) ----
    float ssum[2] = {0.f, 0.f};
    f32x4 o[8][2];
#pragma unroll
    for (int mt = 0; mt < 8; ++mt)
#pragma unroll
        for (int nt = 0; nt < 2; ++nt) o[mt][nt] = (f32x4){0.f, 0.f, 0.f, 0.f};

#pragma unroll
    for (int i = 0; i < 7; ++i) {
        const int kxr = qx - 3 + i;
        const int kxc = min(max(kxr, 0), 31);
        const bool cval = (kxr == kxc);
        f32x4 acc[2][2];
#pragma unroll
        for (int mt = 0; mt < 2; ++mt)
#pragma unroll
            for (int nt = 0; nt < 2; ++nt) acc[mt][nt] = (f32x4){0.f, 0.f, 0.f, 0.f};
#pragma unroll
        for (int kk = 0; kk < 4; ++kk)
#pragma unroll
            for (int mt = 0; mt < 2; ++mt) {
                bf16x8 ka = *(const bf16x8*)(kT + (btNN + kxc * 32 + 16 * mt + l15) * CC + 32 * kk + 8 * g);
#pragma unroll
                for (int nt = 0; nt < 2; ++nt)
                    acc[mt][nt] = __builtin_amdgcn_mfma_f32_16x16x32_bf16(
                        ka, __builtin_bit_cast(bf16x8, ql[nt][kk]), acc[mt][nt], 0, 0, 0);
            }
        // P' packed in-register: element j of pun[nt] = quad (mt=j>=4) r=j&3
        u16x8 pun[2];
#pragma unroll
        for (int mt = 0; mt < 2; ++mt) {
            f32x4 ee4 = *(const f32x4*)(eexp + btNN + kxc * 32 + 16 * mt + 4 * g);
            f32x4 d4;
#pragma unroll
            for (int r = 0; r < 4; ++r) d4[r] = dscale * ee4[r];
#pragma unroll
            for (int nt = 0; nt < 2; ++nt) {
                const int qyv = l15 + 16 * nt;
#pragma unroll
                for (int r = 0; r < 4; ++r) {
                    const float s = (d4[r] * acc[mt][nt][r] + qbk[nt]) * invsq;
                    const int ky = 16 * mt + 4 * g + r;
                    const int dy = ky - qyv;
                    const bool vld = cval && (dy >= -3) && (dy <= 3);
                    const float e = vld ? __expf(s) : 0.f;
                    ssum[nt] += e;
                    pun[nt][mt * 4 + r] = f2b(e * d4[r]);
                }
            }
        }
        // PV: vN is sigma-permuted so slot 8g+j == pun element j
#pragma unroll
        for (int mt = 0; mt < 8; ++mt) {
            bf16x8 va = *(const bf16x8*)(vN + ((size_t)bt * CC + 16 * mt + l15) * NN + kxc * 32 + 8 * g);
#pragma unroll
            for (int nt = 0; nt < 2; ++nt)
                o[mt][nt] = __builtin_amdgcn_mfma_f32_16x16x32_bf16(
                    va, __builtin_bit_cast(bf16x8, pun[nt]), o[mt][nt], 0, 0, 0);
        }
    }
    float inv[2];
#pragma unroll
    for (int nt = 0; nt < 2; ++nt) {
        float s = ssum[nt];
        s += __shfl_xor(s, 16);
        s += __shfl_xor(s, 32);
        inv[nt] = 1.0f / s;
    }

    // ---- att in-register: ov[mt][nt] = bf16(o*inv + bv) ----
    u16x4 ov[8][2];
#pragma unroll
    for (int mt = 0; mt < 8; ++mt) {
        f32x4 bv4 = *(const f32x4*)(bv + 16 * mt + 4 * g);
#pragma unroll
        for (int nt = 0; nt < 2; ++nt)
#pragma unroll
            for (int r = 0; r < 4; ++r)
                ov[mt][nt][r] = f2b(o[mt][nt][r] * inv[nt] + bv4[r]);
    }
    // conv B-frags: WfB is pi2-permuted so cb[kk] = [ov[2kk], ov[2kk+1]]
    bf16x8 cb[4][2];
#pragma unroll
    for (int kk = 0; kk < 4; ++kk)
#pragma unroll
        for (int nt = 0; nt < 2; ++nt) {
            u16x8 cc;
#pragma unroll
            for (int j = 0; j < 4; ++j) {
                cc[j] = ov[2 * kk][nt][j];
                cc[4 + j] = ov[2 * kk + 1][nt][j];
            }
            cb[kk][nt] = __builtin_bit_cast(bf16x8, cc);
        }

    // ---- conv + LIF in 4 c-quarters ----
    const int cl = t >> 3, n4 = (t & 7) * 4;  // LIF ownership
#pragma unroll
    for (int cr = 0; cr < 4; ++cr) {
#pragma unroll
        for (int oi = 0; oi < 2; ++oi) {
            const int ot = 2 * cr + oi;
            f32x4 ca[2];
#pragma unroll
            for (int nt = 0; nt < 2; ++nt) ca[nt] = *(const f32x4*)(bf + 16 * ot + 4 * g);
#pragma unroll
            for (int kk = 0; kk < 4; ++kk) {
                bf16x8 afr = ldA(WfB, ot, kk, l);
#pragma unroll
                for (int nt = 0; nt < 2; ++nt)
                    ca[nt] = __builtin_amdgcn_mfma_f32_16x16x32_bf16(afr, cb[kk][nt], ca[nt], 0, 0, 0);
            }
#pragma unroll
            for (int nt = 0; nt < 2; ++nt)
#pragma unroll
                for (int r = 0; r < 4; ++r)
                    convq[w * 32 * CQS + (16 * oi + 4 * g + r) * CQS + 16 * nt + l15] = ca[nt][r];
        }
        __syncthreads();
        // LIF over tt for c = 32*cr + cl, n = qx*32 + n4..n4+3
        f32x4 mem = {0.f, 0.f, 0.f, 0.f};
#pragma unroll
        for (int tt = 0; tt < 4; ++tt) {
            f32x4 x = *(const f32x4*)&convq[tt * 32 * CQS + cl * CQS + n4];
            f32x4 mv = mem * 0.5f + x;
            float4 sp;
            sp.x = (mv[0] > 1.0f) ? 1.0f : 0.0f; if (mv[0] > 1.0f) mv[0] = 0.f;
            sp.y = (mv[1] > 1.0f) ? 1.0f : 0.0f; if (mv[1] > 1.0f) mv[1] = 0.f;
            sp.z = (mv[2] > 1.0f) ? 1.0f : 0.0f; if (mv[2] > 1.0f) mv[2] = 0.f;
            sp.w = (mv[3] > 1.0f) ? 1.0f : 0.0f; if (mv[3] > 1.0f) mv[3] = 0.f;
            *(float4*)(out + ((size_t)(b * 4 + tt) * CC + 32 * cr + cl) * NN + qx * 32 + n4) = sp;
            mem = mv;
        }
        __syncthreads();
    }
}

extern "C" void kernel_launch(void* const* d_in, const int* in_sizes, int n_in,
                              void* d_out, int out_size, void* d_ws, size_t ws_size,
                              hipStream_t stream) {
    (void)in_sizes; (void)n_in; (void)out_size; (void)ws_size;
    const float* edge = (const float*)d_in[0];
    const float* dvs  = (const float*)d_in[1];
    const float* We = (const float*)d_in[2];
    const float* be = (const float*)d_in[3];
    const float* Wd = (const float*)d_in[4];
    const float* bd = (const float*)d_in[5];
    const float* Wq = (const float*)d_in[6];
    const float* bq = (const float*)d_in[7];
    const float* Wk = (const float*)d_in[8];
    const float* bk = (const float*)d_in[9];
    const float* Wv = (const float*)d_in[10];
    const float* bv = (const float*)d_in[11];
    const float* Wf = (const float*)d_in[12];
    const float* bf = (const float*)d_in[13];
    float* out = (float*)d_out;

    const size_t S = (size_t)BTOT * NN * CC;  // 4.19M elems
    u16* qT   = (u16*)d_ws;
    u16* kT   = qT + S;
    u16* vN   = kT + S;
    u16* WbAll = vN + S;                      // 6 * 16384 u16
    float* fbase = (float*)(WbAll + 6 * 16384);
    float* cvec  = fbase;                     // 3 * 128
    float* eexp  = cvec + 3 * CC;             // BTOT*NN
    float* partial = eexp + BTOT * NN;        // BTOT*16
    u16* WeB  = WbAll + 0 * 16384;
    u16* WdB  = WbAll + 1 * 16384;
    u16* WqeB = WbAll + 2 * 16384;
    u16* WkdB = WbAll + 3 * 16384;
    u16* WvdB = WbAll + 4 * 16384;
    u16* WfB  = WbAll + 5 * 16384;
    float* cq = cvec;
    float* ck = cvec + CC;
    float* cv = cvec + 2 * CC;

    k_prep<<<216, 256, 0, stream>>>(We, Wd, Wf, Wq, Wk, Wv, be, bd, WbAll, cvec);
    k_front<<<512, 256, 0, stream>>>(edge, dvs, WeB, WdB, WqeB, WkdB, WvdB,
                                     be, bd, bq, cq, ck, cv, eexp, partial, qT, kT, vN);
    k_attnf<<<256, 256, 0, stream>>>(qT, kT, vN, eexp, partial, bk, bv, WfB, bf, out);
}

// Round 12
// 64.850 us; speedup vs baseline: 1.0754x; 1.0754x over previous
//
#include <hip/hip_runtime.h>
#include <math.h>

#define CC 128   // channels
#define NN 1024  // H*W
#define BTOT 32  // B*T
#define CP 152   // k_front LDS row stride (bf16 elems)
#define PSTs 40  // P column-buffer row stride (u16): 80B
#define CPA 136  // att_lds row stride (u16): 272B = 17*16
#define CQS 36   // conv_q row stride (f32): 144B = 9*16

typedef unsigned short u16;
typedef u16 u16x8 __attribute__((ext_vector_type(8)));
typedef u16 u16x4 __attribute__((ext_vector_type(4)));
typedef __bf16 bf16x8 __attribute__((ext_vector_type(8)));
typedef float f32x4 __attribute__((ext_vector_type(4)));

__device__ __forceinline__ u16 f2b(float f) {
    unsigned int u = __float_as_uint(f);
    u += 0x7FFFu + ((u >> 16) & 1u);   // RNE
    return (u16)(u >> 16);
}
__device__ __forceinline__ float b2f(u16 u) {
    return __uint_as_float(((unsigned int)u) << 16);
}

// ---------- MFMA helpers ----------
// A-frag: lane l holds A[16*ot + (l&15)][32*kk + 8*(l>>4) + j], j=0..7.
// B-frag: lane l holds B[16*nt + (l&15)][32*kk + 8*(l>>4) + j].
// C/D: col = l&15 (B row), row = (l>>4)*4 + r (+16*ot) (A row).
__device__ __forceinline__ void loadB(const u16* brow, int g, bf16x8 bfr[4]) {
#pragma unroll
    for (int kk = 0; kk < 4; ++kk)
        bfr[kk] = *(const bf16x8*)(brow + kk * 32 + g * 8);
}
__device__ __forceinline__ bf16x8 ldA(const u16* __restrict__ WB, int ot, int kk, int l) {
    return *(const bf16x8*)(WB + ((size_t)(ot * 4 + kk) * 64 + l) * 8);
}

// ---------- kernel 0: prep — pack We/Wd/Wf AND compose+pack Wqe/Wkd/Wvd ----------
__global__ __launch_bounds__(256) void k_prep(
    const float* __restrict__ We, const float* __restrict__ Wd,
    const float* __restrict__ Wf, const float* __restrict__ Wq,
    const float* __restrict__ Wk, const float* __restrict__ Wv,
    const float* __restrict__ be, const float* __restrict__ bd,
    u16* __restrict__ out, float* __restrict__ cvec)
{
    const int bid = blockIdx.x, t = threadIdx.x;
    if (bid < 24) {
        // plain pack: We->slot0, Wd->slot1, Wf->slot5
        const int gid = bid * 256 + t;       // 0..6143
        const int wi = gid >> 11;            // 0..2
        const float* W = (wi == 0) ? We : (wi == 1) ? Wd : Wf;
        const int slot = (wi == 2) ? 5 : wi;
        const int rem = gid & 2047;
        const int ot = rem >> 8, kk = (rem >> 6) & 3, l = rem & 63;
        const int row = ot * 16 + (l & 15), col = kk * 32 + (l >> 4) * 8;
        float4 a = *(const float4*)(W + row * CC + col);
        float4 b = *(const float4*)(W + row * CC + col + 4);
        u16x8 u;
        u[0] = f2b(a.x); u[1] = f2b(a.y); u[2] = f2b(a.z); u[3] = f2b(a.w);
        u[4] = f2b(b.x); u[5] = f2b(b.y); u[6] = f2b(b.z); u[7] = f2b(b.w);
        *(u16x8*)(out + (size_t)slot * 16384 + ((size_t)(ot * 4 + kk) * 64 + l) * 8) = u;
    } else {
        // compose: Wqe=Wq*We (slot2), Wkd=Wk*Wd (slot3), Wvd=Wv*Wd (slot4)
        const int cid = bid - 24;            // 0..191
        const int mat = cid >> 6;            // 0..2
        const int o = ((cid & 63) << 1) | (t >> 7);
        const int c = t & 127;
        const float* A = (mat == 0) ? Wq : (mat == 1) ? Wk : Wv;
        const float* B = (mat == 0) ? We : Wd;
        const float* bvec = (mat == 0) ? be : bd;
        float acc = 0.f;
        for (int m = 0; m < CC; ++m) acc += A[o * CC + m] * B[m * CC + c];
        const int ot = o >> 4, l15o = o & 15;
        const int kk = c >> 5, gc = (c >> 3) & 3, j = c & 7;
        const int l = gc * 16 + l15o;
        out[(size_t)(2 + mat) * 16384 + ((size_t)(ot * 4 + kk) * 64 + l) * 8 + j] = f2b(acc);
        if (c == 0) {
            float bacc = 0.f;
            for (int m = 0; m < CC; ++m) bacc += A[o * CC + m] * bvec[m];
            cvec[mat * CC + o] = bacc;
        }
    }
}

// ---------- kernel 1: front — 64-n tiles, XCD-aligned grid ----------
// 1D grid of 512: bt = (id&7)*4 + ((id>>3)&3), tile = id>>5.
// Also emits eexp = exp(l2e) per n and per-block partial sums of eexp
// (deterministic shfl-tree), replacing the separate k_dens kernel.
__global__ __launch_bounds__(256) void k_front(
    const float* __restrict__ edge, const float* __restrict__ dvs,
    const u16* __restrict__ WeB, const u16* __restrict__ WdB,
    const u16* __restrict__ WqeB, const u16* __restrict__ WkdB,
    const u16* __restrict__ WvdB,
    const float* __restrict__ be, const float* __restrict__ bd,
    const float* __restrict__ bq,
    const float* __restrict__ cq, const float* __restrict__ ck,
    const float* __restrict__ cv,
    float* __restrict__ eexp_out, float* __restrict__ partial,
    u16* __restrict__ qT, u16* __restrict__ kT, u16* __restrict__ vN)
{
    __shared__ u16 bufA[64 * CP];
    __shared__ u16 bufB[64 * CP];
    __shared__ float redp[4];
    const int t = threadIdx.x;
    const int id = blockIdx.x;
    const int bt = (id & 7) * 4 + ((id >> 3) & 3);
    const int n0b = (id >> 5) * 64;
    const float* eb = edge + (size_t)bt * CC * NN + n0b;
    const float* db = dvs + (size_t)bt * CC * NN + n0b;

    // stage: transpose [c][n] fp32 -> [n][c] bf16
#pragma unroll
    for (int j = 0; j < 2; ++j) {
        const int i = t + 256 * j;
        const int c4 = i >> 4, p = i & 15;
        float4 e[4], d[4];
#pragma unroll
        for (int m = 0; m < 4; ++m) {
            e[m] = *(const float4*)(eb + (size_t)(4 * c4 + m) * NN + 4 * p);
            d[m] = *(const float4*)(db + (size_t)(4 * c4 + m) * NN + 4 * p);
        }
#pragma unroll
        for (int n = 0; n < 4; ++n) {
            u16x4 ue, ud;
            ue[0] = f2b(((const float*)&e[0])[n]); ud[0] = f2b(((const float*)&d[0])[n]);
            ue[1] = f2b(((const float*)&e[1])[n]); ud[1] = f2b(((const float*)&d[1])[n]);
            ue[2] = f2b(((const float*)&e[2])[n]); ud[2] = f2b(((const float*)&d[2])[n]);
            ue[3] = f2b(((const float*)&e[3])[n]); ud[3] = f2b(((const float*)&d[3])[n]);
            *(u16x4*)&bufA[(4 * p + n) * CP + 4 * c4] = ue;
            *(u16x4*)&bufB[(4 * p + n) * CP + 4 * c4] = ud;
        }
    }
    __syncthreads();

    const int w = t >> 6, l = t & 63;
    const int l15 = l & 15, g = l >> 4;
    const int nloc = w * 16 + l15;
    const size_t gn = (size_t)bt * NN + n0b + nloc;

    bf16x8 bfrE[4], bfrD[4];
    loadB(bufA + nloc * CP, g, bfrE);
    loadB(bufB + nloc * CP, g, bfrD);

    // --- ef/df accumulators (stats only, never materialized) ---
    f32x4 aE[8], aD[8];
#pragma unroll
    for (int ot = 0; ot < 8; ++ot) {
        aE[ot] = *(const f32x4*)(be + 16 * ot + 4 * g);
        aD[ot] = *(const f32x4*)(bd + 16 * ot + 4 * g);
    }
#pragma unroll
    for (int ot = 0; ot < 8; ++ot)
#pragma unroll
        for (int kk = 0; kk < 4; ++kk) {
            aE[ot] = __builtin_amdgcn_mfma_f32_16x16x32_bf16(ldA(WeB, ot, kk, l), bfrE[kk], aE[ot], 0, 0, 0);
            aD[ot] = __builtin_amdgcn_mfma_f32_16x16x32_bf16(ldA(WdB, ot, kk, l), bfrD[kk], aD[ot], 0, 0, 0);
        }
    float s2e = 0.f, s2d = 0.f, sed = 0.f;
#pragma unroll
    for (int ot = 0; ot < 8; ++ot)
#pragma unroll
        for (int r = 0; r < 4; ++r) {
            const float fe = aE[ot][r], fd = aD[ot][r];
            s2e += fe * fe; s2d += fd * fd; sed += fe * fd;
        }
    s2e += __shfl_xor(s2e, 16); s2e += __shfl_xor(s2e, 32);
    s2d += __shfl_xor(s2d, 16); s2d += __shfl_xor(s2d, 32);
    sed += __shfl_xor(sed, 16); sed += __shfl_xor(sed, 32);
    const float le = sqrtf(s2e), ld = sqrtf(s2d);
    const float sim = (sed / ((le + 1e-6f) * (ld + 1e-6f)) + 1.0f) * 0.5f;
    // eexp = exp(l2e) (no max-shift: le <= ~35 so e^le well within fp32)
    const float ee = __expf(le);
    if (g == 0) eexp_out[gn] = ee;
    // wave partial sum over 16 distinct n (xor 1,2,4,8 stays within g-group;
    // each group holds identical values, so result = sum over l15)
    {
        float s = ee;
        s += __shfl_xor(s, 1); s += __shfl_xor(s, 2);
        s += __shfl_xor(s, 4); s += __shfl_xor(s, 8);
        if (l == 0) redp[w] = s;
    }

    // --- q = sim*(Wqe*e + cq) + bq ---
    {
        f32x4 aQ[8];
#pragma unroll
        for (int ot = 0; ot < 8; ++ot) aQ[ot] = *(const f32x4*)(cq + 16 * ot + 4 * g);
#pragma unroll
        for (int ot = 0; ot < 8; ++ot)
#pragma unroll
            for (int kk = 0; kk < 4; ++kk)
                aQ[ot] = __builtin_amdgcn_mfma_f32_16x16x32_bf16(ldA(WqeB, ot, kk, l), bfrE[kk], aQ[ot], 0, 0, 0);
#pragma unroll
        for (int ot = 0; ot < 8; ++ot) {
            f32x4 b4 = *(const f32x4*)(bq + 16 * ot + 4 * g);
            u16x4 u;
#pragma unroll
            for (int r = 0; r < 4; ++r) u[r] = f2b(sim * aQ[ot][r] + b4[r]);
            *(u16x4*)(qT + gn * CC + 16 * ot + 4 * g) = u;
        }
    }
    // --- kraw = Wkd*d + ck ---
    {
        f32x4 aK[8];
#pragma unroll
        for (int ot = 0; ot < 8; ++ot) aK[ot] = *(const f32x4*)(ck + 16 * ot + 4 * g);
#pragma unroll
        for (int ot = 0; ot < 8; ++ot)
#pragma unroll
            for (int kk = 0; kk < 4; ++kk)
                aK[ot] = __builtin_amdgcn_mfma_f32_16x16x32_bf16(ldA(WkdB, ot, kk, l), bfrD[kk], aK[ot], 0, 0, 0);
#pragma unroll
        for (int ot = 0; ot < 8; ++ot) {
            u16x4 u;
#pragma unroll
            for (int r = 0; r < 4; ++r) u[r] = f2b(aK[ot][r]);
            *(u16x4*)(kT + gn * CC + 16 * ot + 4 * g) = u;
        }
    }
    // --- vraw = Wvd*d + cv ; channel-major vN[c][n] via LDS transpose ---
    {
        f32x4 aV[8];
#pragma unroll
        for (int ot = 0; ot < 8; ++ot) aV[ot] = *(const f32x4*)(cv + 16 * ot + 4 * g);
#pragma unroll
        for (int ot = 0; ot < 8; ++ot)
#pragma unroll
            for (int kk = 0; kk < 4; ++kk)
                aV[ot] = __builtin_amdgcn_mfma_f32_16x16x32_bf16(ldA(WvdB, ot, kk, l), bfrD[kk], aV[ot], 0, 0, 0);
        __syncthreads();  // bufA reads (loadB) all done; redp written
        if (t == 0)
            partial[(size_t)bt * 16 + (id >> 5)] = redp[0] + redp[1] + redp[2] + redp[3];
        u16* bufT = bufA; // [128][72] u16 = 9216 <= 64*CP
#pragma unroll
        for (int ot = 0; ot < 8; ++ot)
#pragma unroll
            for (int r = 0; r < 4; ++r)
                bufT[(16 * ot + 4 * g + r) * 72 + nloc] = f2b(aV[ot][r]);
        __syncthreads();
#pragma unroll
        for (int p = 0; p < 4; ++p) {
            const int idx = t + 256 * p;
            const int c = idx >> 3, n8 = (idx & 7) * 8;
            *(u16x8*)(vN + ((size_t)bt * CC + c) * NN + n0b + n8) =
                *(const u16x8*)&bufT[c * 72 + n8];
        }
    }
}

// ---------- kernel 2: FUSED attention + output conv + LIF ----------
// block = (b, qx); wave w = time step tt; bt = b*4+w.
// dens computed on the fly: dens[n] = (1024/S) * eexp[n], S = sum of 16 partials.
__global__ __launch_bounds__(256) void k_attnf(
    const u16* __restrict__ qT, const u16* __restrict__ kT,
    const u16* __restrict__ vN, const float* __restrict__ eexp,
    const float* __restrict__ partial,
    const float* __restrict__ bk, const float* __restrict__ bv,
    const u16* __restrict__ WfB, const float* __restrict__ bf,
    float* __restrict__ out)
{
    __shared__ u16 lds_u16[26624];  // 53248 B total
    const int t = threadIdx.x;
    const int id = blockIdx.x;
    const int b = id & 7, qx = id >> 3;   // XCD x owns b = x (matches k_front)
    const int w = t >> 6;
    const int bt = b * 4 + w;
    const int l = t & 63, l15 = l & 15, g = l >> 4;
    u16* att = lds_u16;                                   // [4][32][CPA]
    float* convq = (float*)(lds_u16 + 17408);             // [4][32][CQS] f32
    u16* P = lds_u16 + w * 32 * PSTs;                     // overlays att region
    const size_t btNN = (size_t)bt * NN;
    const float invsq = 0.08838834764831843f;  // 1/sqrt(128)

    // softmax denom for this bt (fixed order -> deterministic)
    float S = 0.f;
    {
        const float* pp = partial + (size_t)bt * 16;
#pragma unroll
        for (int i = 0; i < 16; ++i) S += pp[i];
    }
    const float dscale = 1024.0f / S;

    // q fragments
    u16x8 ql[2][4];
#pragma unroll
    for (int nt = 0; nt < 2; ++nt)
#pragma unroll
        for (int kk = 0; kk < 4; ++kk)
            ql[nt][kk] = *(const u16x8*)(qT + (btNN + qx * 32 + 16 * nt + l15) * CC + 32 * kk + 8 * g);

    // qbk[nt] = q[qy]·bk
    float qbk[2] = {0.f, 0.f};
#pragma unroll
    for (int kk = 0; kk < 4; ++kk) {
        f32x4 b0 = *(const f32x4*)(bk + 32 * kk + 8 * g);
        f32x4 b1 = *(const f32x4*)(bk + 32 * kk + 8 * g + 4);
#pragma unroll
        for (int nt = 0; nt < 2; ++nt)
#pragma unroll
            for (int j = 0; j < 4; ++j) {
                qbk[nt] += b2f(ql[nt][kk][j]) * b0[j];
                qbk[nt] += b2f(ql[nt][kk][4 + j]) * b1[j];
            }
    }
#pragma unroll
    for (int nt = 0; nt < 2; ++nt) {
        qbk[nt] += __shfl_xor(qbk[nt], 16);
        qbk[nt] += __shfl_xor(qbk[nt], 32);
    }

    // ---- interleaved QK^T / P' / PV over the 7 kx columns ----
    float ssum[2] = {0.f, 0.f};
    f32x4 o[8][2];
#pragma unroll
    for (int mt = 0; mt < 8; ++mt)
#pragma unroll
        for (int nt = 0; nt < 2; ++nt) o[mt][nt] = (f32x4){0.f, 0.f, 0.f, 0.f};

#pragma unroll
    for (int i = 0; i < 7; ++i) {
        const int kxr = qx - 3 + i;
        const int kxc = min(max(kxr, 0), 31);
        const bool cval = (kxr == kxc);
        f32x4 acc[2][2];
#pragma unroll
        for (int mt = 0; mt < 2; ++mt)
#pragma unroll
            for (int nt = 0; nt < 2; ++nt) acc[mt][nt] = (f32x4){0.f, 0.f, 0.f, 0.f};
#pragma unroll
        for (int kk = 0; kk < 4; ++kk)
#pragma unroll
            for (int mt = 0; mt < 2; ++mt) {
                bf16x8 ka = *(const bf16x8*)(kT + (btNN + kxc * 32 + 16 * mt + l15) * CC + 32 * kk + 8 * g);
#pragma unroll
                for (int nt = 0; nt < 2; ++nt)
                    acc[mt][nt] = __builtin_amdgcn_mfma_f32_16x16x32_bf16(
                        ka, __builtin_bit_cast(bf16x8, ql[nt][kk]), acc[mt][nt], 0, 0, 0);
            }
#pragma unroll
        for (int mt = 0; mt < 2; ++mt) {
            f32x4 ee4 = *(const f32x4*)(eexp + btNN + kxc * 32 + 16 * mt + 4 * g);
            f32x4 d4;
#pragma unroll
            for (int r = 0; r < 4; ++r) d4[r] = dscale * ee4[r];
#pragma unroll
            for (int nt = 0; nt < 2; ++nt) {
                const int qyv = l15 + 16 * nt;
                u16x4 pw;
#pragma unroll
                for (int r = 0; r < 4; ++r) {
                    const float s = (d4[r] * acc[mt][nt][r] + qbk[nt]) * invsq;
                    const int ky = 16 * mt + 4 * g + r;
                    const int dy = ky - qyv;
                    const bool vld = cval && (dy >= -3) && (dy <= 3);
                    const float e = vld ? __expf(s) : 0.f;
                    ssum[nt] += e;
                    pw[r] = f2b(e * d4[r]);
                }
                *(u16x4*)&P[qyv * PSTs + 16 * mt + 4 * g] = pw;
            }
        }
        asm volatile("s_waitcnt lgkmcnt(0)" ::: "memory");
        __builtin_amdgcn_sched_barrier(0);
        bf16x8 pb[2];
#pragma unroll
        for (int nt = 0; nt < 2; ++nt)
            pb[nt] = *(const bf16x8*)&P[(16 * nt + l15) * PSTs + 8 * g];
#pragma unroll
        for (int mt = 0; mt < 8; ++mt) {
            bf16x8 va = *(const bf16x8*)(vN + ((size_t)bt * CC + 16 * mt + l15) * NN + kxc * 32 + 8 * g);
#pragma unroll
            for (int nt = 0; nt < 2; ++nt)
                o[mt][nt] = __builtin_amdgcn_mfma_f32_16x16x32_bf16(va, pb[nt], o[mt][nt], 0, 0, 0);
        }
    }
    float inv[2];
#pragma unroll
    for (int nt = 0; nt < 2; ++nt) {
        float s = ssum[nt];
        s += __shfl_xor(s, 16);
        s += __shfl_xor(s, 32);
        inv[nt] = 1.0f / s;
    }

    __syncthreads();  // all P reads done before att overwrites the region

    // ---- O -> att_lds[w][n][c] bf16 (inv scale + bv) ----
    u16* attw = att + w * 32 * CPA;
#pragma unroll
    for (int mt = 0; mt < 8; ++mt) {
        f32x4 bv4 = *(const f32x4*)(bv + 16 * mt + 4 * g);
#pragma unroll
        for (int nt = 0; nt < 2; ++nt) {
            u16x4 ov;
#pragma unroll
            for (int r = 0; r < 4; ++r) ov[r] = f2b(o[mt][nt][r] * inv[nt] + bv4[r]);
            *(u16x4*)&attw[(16 * nt + l15) * CPA + 16 * mt + 4 * g] = ov;
        }
    }
    asm volatile("s_waitcnt lgkmcnt(0)" ::: "memory");
    __builtin_amdgcn_sched_barrier(0);

    // conv B-frags from own wave's att slice
    bf16x8 cb[4][2];
#pragma unroll
    for (int kk = 0; kk < 4; ++kk)
#pragma unroll
        for (int nt = 0; nt < 2; ++nt)
            cb[kk][nt] = *(const bf16x8*)&attw[(16 * nt + l15) * CPA + 32 * kk + 8 * g];

    // ---- conv + LIF in 4 c-quarters ----
    const int cl = t >> 3, n4 = (t & 7) * 4;  // LIF ownership
#pragma unroll
    for (int cr = 0; cr < 4; ++cr) {
#pragma unroll
        for (int oi = 0; oi < 2; ++oi) {
            const int ot = 2 * cr + oi;
            f32x4 ca[2];
#pragma unroll
            for (int nt = 0; nt < 2; ++nt) ca[nt] = *(const f32x4*)(bf + 16 * ot + 4 * g);
#pragma unroll
            for (int kk = 0; kk < 4; ++kk) {
                bf16x8 afr = ldA(WfB, ot, kk, l);
#pragma unroll
                for (int nt = 0; nt < 2; ++nt)
                    ca[nt] = __builtin_amdgcn_mfma_f32_16x16x32_bf16(afr, cb[kk][nt], ca[nt], 0, 0, 0);
            }
#pragma unroll
            for (int nt = 0; nt < 2; ++nt)
#pragma unroll
                for (int r = 0; r < 4; ++r)
                    convq[w * 32 * CQS + (16 * oi + 4 * g + r) * CQS + 16 * nt + l15] = ca[nt][r];
        }
        __syncthreads();
        // LIF over tt for c = 32*cr + cl, n = qx*32 + n4..n4+3
        f32x4 mem = {0.f, 0.f, 0.f, 0.f};
#pragma unroll
        for (int tt = 0; tt < 4; ++tt) {
            f32x4 x = *(const f32x4*)&convq[tt * 32 * CQS + cl * CQS + n4];
            f32x4 mv = mem * 0.5f + x;
            float4 sp;
            sp.x = (mv[0] > 1.0f) ? 1.0f : 0.0f; if (mv[0] > 1.0f) mv[0] = 0.f;
            sp.y = (mv[1] > 1.0f) ? 1.0f : 0.0f; if (mv[1] > 1.0f) mv[1] = 0.f;
            sp.z = (mv[2] > 1.0f) ? 1.0f : 0.0f; if (mv[2] > 1.0f) mv[2] = 0.f;
            sp.w = (mv[3] > 1.0f) ? 1.0f : 0.0f; if (mv[3] > 1.0f) mv[3] = 0.f;
            *(float4*)(out + ((size_t)(b * 4 + tt) * CC + 32 * cr + cl) * NN + qx * 32 + n4) = sp;
            mem = mv;
        }
        __syncthreads();
    }
}

extern "C" void kernel_launch(void* const* d_in, const int* in_sizes, int n_in,
                              void* d_out, int out_size, void* d_ws, size_t ws_size,
                              hipStream_t stream) {
    (void)in_sizes; (void)n_in; (void)out_size; (void)ws_size;
    const float* edge = (const float*)d_in[0];
    const float* dvs  = (const float*)d_in[1];
    const float* We = (const float*)d_in[2];
    const float* be = (const float*)d_in[3];
    const float* Wd = (const float*)d_in[4];
    const float* bd = (const float*)d_in[5];
    const float* Wq = (const float*)d_in[6];
    const float* bq = (const float*)d_in[7];
    const float* Wk = (const float*)d_in[8];
    const float* bk = (const float*)d_in[9];
    const float* Wv = (const float*)d_in[10];
    const float* bv = (const float*)d_in[11];
    const float* Wf = (const float*)d_in[12];
    const float* bf = (const float*)d_in[13];
    float* out = (float*)d_out;

    const size_t S = (size_t)BTOT * NN * CC;  // 4.19M elems
    u16* qT   = (u16*)d_ws;
    u16* kT   = qT + S;
    u16* vN   = kT + S;
    u16* WbAll = vN + S;                      // 6 * 16384 u16
    float* fbase = (float*)(WbAll + 6 * 16384);
    float* cvec  = fbase;                     // 3 * 128
    float* eexp  = cvec + 3 * CC;             // BTOT*NN
    float* partial = eexp + BTOT * NN;        // BTOT*16
    u16* WeB  = WbAll + 0 * 16384;
    u16* WdB  = WbAll + 1 * 16384;
    u16* WqeB = WbAll + 2 * 16384;
    u16* WkdB = WbAll + 3 * 16384;
    u16* WvdB = WbAll + 4 * 16384;
    u16* WfB  = WbAll + 5 * 16384;
    float* cq = cvec;
    float* ck = cvec + CC;
    float* cv = cvec + 2 * CC;

    k_prep<<<216, 256, 0, stream>>>(We, Wd, Wf, Wq, Wk, Wv, be, bd, WbAll, cvec);
    k_front<<<512, 256, 0, stream>>>(edge, dvs, WeB, WdB, WqeB, WkdB, WvdB,
                                     be, bd, bq, cq, ck, cv, eexp, partial, qT, kT, vN);
    k_attnf<<<256, 256, 0, stream>>>(qT, kT, vN, eexp, partial, bk, bv, WfB, bf, out);
}

// Round 13
// 64.052 us; speedup vs baseline: 1.0887x; 1.0124x over previous
//
#include <hip/hip_runtime.h>
#include <math.h>

#define CC 128   // channels
#define NN 1024  // H*W
#define BTOT 32  // B*T
#define CP 152   // k_front LDS row stride (bf16 elems)
#define PSTs 40  // P column-buffer row stride (u16): 80B
#define CPA 136  // att_lds row stride (u16): 272B = 17*16
#define CQS 36   // conv_q row stride (f32): 144B = 9*16
#define SQS 33   // o-exchange scratch row stride (f32), padded: conflict-free

typedef unsigned short u16;
typedef u16 u16x8 __attribute__((ext_vector_type(8)));
typedef u16 u16x4 __attribute__((ext_vector_type(4)));
typedef __bf16 bf16x8 __attribute__((ext_vector_type(8)));
typedef float f32x4 __attribute__((ext_vector_type(4)));

__device__ __forceinline__ u16 f2b(float f) {
    unsigned int u = __float_as_uint(f);
    u += 0x7FFFu + ((u >> 16) & 1u);   // RNE
    return (u16)(u >> 16);
}
__device__ __forceinline__ float b2f(u16 u) {
    return __uint_as_float(((unsigned int)u) << 16);
}

// ---------- MFMA helpers ----------
// A-frag: lane l holds A[16*ot + (l&15)][32*kk + 8*(l>>4) + j], j=0..7.
// B-frag: lane l holds B[16*nt + (l&15)][32*kk + 8*(l>>4) + j].
// C/D: col = l&15 (B row), row = (l>>4)*4 + r (+16*ot) (A row).
__device__ __forceinline__ void loadB(const u16* brow, int g, bf16x8 bfr[4]) {
#pragma unroll
    for (int kk = 0; kk < 4; ++kk)
        bfr[kk] = *(const bf16x8*)(brow + kk * 32 + g * 8);
}
__device__ __forceinline__ bf16x8 ldA(const u16* __restrict__ WB, int ot, int kk, int l) {
    return *(const bf16x8*)(WB + ((size_t)(ot * 4 + kk) * 64 + l) * 8);
}

// ---------- kernel 0: prep — pack We/Wd/Wf AND compose+pack Wqe/Wkd/Wvd ----------
__global__ __launch_bounds__(256) void k_prep(
    const float* __restrict__ We, const float* __restrict__ Wd,
    const float* __restrict__ Wf, const float* __restrict__ Wq,
    const float* __restrict__ Wk, const float* __restrict__ Wv,
    const float* __restrict__ be, const float* __restrict__ bd,
    u16* __restrict__ out, float* __restrict__ cvec)
{
    const int bid = blockIdx.x, t = threadIdx.x;
    if (bid < 24) {
        const int gid = bid * 256 + t;       // 0..6143
        const int wi = gid >> 11;            // 0..2
        const float* W = (wi == 0) ? We : (wi == 1) ? Wd : Wf;
        const int slot = (wi == 2) ? 5 : wi;
        const int rem = gid & 2047;
        const int ot = rem >> 8, kk = (rem >> 6) & 3, l = rem & 63;
        const int row = ot * 16 + (l & 15), col = kk * 32 + (l >> 4) * 8;
        float4 a = *(const float4*)(W + row * CC + col);
        float4 b = *(const float4*)(W + row * CC + col + 4);
        u16x8 u;
        u[0] = f2b(a.x); u[1] = f2b(a.y); u[2] = f2b(a.z); u[3] = f2b(a.w);
        u[4] = f2b(b.x); u[5] = f2b(b.y); u[6] = f2b(b.z); u[7] = f2b(b.w);
        *(u16x8*)(out + (size_t)slot * 16384 + ((size_t)(ot * 4 + kk) * 64 + l) * 8) = u;
    } else {
        const int cid = bid - 24;            // 0..191
        const int mat = cid >> 6;            // 0..2
        const int o = ((cid & 63) << 1) | (t >> 7);
        const int c = t & 127;
        const float* A = (mat == 0) ? Wq : (mat == 1) ? Wk : Wv;
        const float* B = (mat == 0) ? We : Wd;
        const float* bvec = (mat == 0) ? be : bd;
        float acc = 0.f;
        for (int m = 0; m < CC; ++m) acc += A[o * CC + m] * B[m * CC + c];
        const int ot = o >> 4, l15o = o & 15;
        const int kk = c >> 5, gc = (c >> 3) & 3, j = c & 7;
        const int l = gc * 16 + l15o;
        out[(size_t)(2 + mat) * 16384 + ((size_t)(ot * 4 + kk) * 64 + l) * 8 + j] = f2b(acc);
        if (c == 0) {
            float bacc = 0.f;
            for (int m = 0; m < CC; ++m) bacc += A[o * CC + m] * bvec[m];
            cvec[mat * CC + o] = bacc;
        }
    }
}

// ---------- kernel 1: front — 64-n tiles, XCD-aligned grid (unchanged R12) ----------
__global__ __launch_bounds__(256) void k_front(
    const float* __restrict__ edge, const float* __restrict__ dvs,
    const u16* __restrict__ WeB, const u16* __restrict__ WdB,
    const u16* __restrict__ WqeB, const u16* __restrict__ WkdB,
    const u16* __restrict__ WvdB,
    const float* __restrict__ be, const float* __restrict__ bd,
    const float* __restrict__ bq,
    const float* __restrict__ cq, const float* __restrict__ ck,
    const float* __restrict__ cv,
    float* __restrict__ eexp_out, float* __restrict__ partial,
    u16* __restrict__ qT, u16* __restrict__ kT, u16* __restrict__ vN)
{
    __shared__ u16 bufA[64 * CP];
    __shared__ u16 bufB[64 * CP];
    __shared__ float redp[4];
    const int t = threadIdx.x;
    const int id = blockIdx.x;
    const int bt = (id & 7) * 4 + ((id >> 3) & 3);
    const int n0b = (id >> 5) * 64;
    const float* eb = edge + (size_t)bt * CC * NN + n0b;
    const float* db = dvs + (size_t)bt * CC * NN + n0b;

#pragma unroll
    for (int j = 0; j < 2; ++j) {
        const int i = t + 256 * j;
        const int c4 = i >> 4, p = i & 15;
        float4 e[4], d[4];
#pragma unroll
        for (int m = 0; m < 4; ++m) {
            e[m] = *(const float4*)(eb + (size_t)(4 * c4 + m) * NN + 4 * p);
            d[m] = *(const float4*)(db + (size_t)(4 * c4 + m) * NN + 4 * p);
        }
#pragma unroll
        for (int n = 0; n < 4; ++n) {
            u16x4 ue, ud;
            ue[0] = f2b(((const float*)&e[0])[n]); ud[0] = f2b(((const float*)&d[0])[n]);
            ue[1] = f2b(((const float*)&e[1])[n]); ud[1] = f2b(((const float*)&d[1])[n]);
            ue[2] = f2b(((const float*)&e[2])[n]); ud[2] = f2b(((const float*)&d[2])[n]);
            ue[3] = f2b(((const float*)&e[3])[n]); ud[3] = f2b(((const float*)&d[3])[n]);
            *(u16x4*)&bufA[(4 * p + n) * CP + 4 * c4] = ue;
            *(u16x4*)&bufB[(4 * p + n) * CP + 4 * c4] = ud;
        }
    }
    __syncthreads();

    const int w = t >> 6, l = t & 63;
    const int l15 = l & 15, g = l >> 4;
    const int nloc = w * 16 + l15;
    const size_t gn = (size_t)bt * NN + n0b + nloc;

    bf16x8 bfrE[4], bfrD[4];
    loadB(bufA + nloc * CP, g, bfrE);
    loadB(bufB + nloc * CP, g, bfrD);

    f32x4 aE[8], aD[8];
#pragma unroll
    for (int ot = 0; ot < 8; ++ot) {
        aE[ot] = *(const f32x4*)(be + 16 * ot + 4 * g);
        aD[ot] = *(const f32x4*)(bd + 16 * ot + 4 * g);
    }
#pragma unroll
    for (int ot = 0; ot < 8; ++ot)
#pragma unroll
        for (int kk = 0; kk < 4; ++kk) {
            aE[ot] = __builtin_amdgcn_mfma_f32_16x16x32_bf16(ldA(WeB, ot, kk, l), bfrE[kk], aE[ot], 0, 0, 0);
            aD[ot] = __builtin_amdgcn_mfma_f32_16x16x32_bf16(ldA(WdB, ot, kk, l), bfrD[kk], aD[ot], 0, 0, 0);
        }
    float s2e = 0.f, s2d = 0.f, sed = 0.f;
#pragma unroll
    for (int ot = 0; ot < 8; ++ot)
#pragma unroll
        for (int r = 0; r < 4; ++r) {
            const float fe = aE[ot][r], fd = aD[ot][r];
            s2e += fe * fe; s2d += fd * fd; sed += fe * fd;
        }
    s2e += __shfl_xor(s2e, 16); s2e += __shfl_xor(s2e, 32);
    s2d += __shfl_xor(s2d, 16); s2d += __shfl_xor(s2d, 32);
    sed += __shfl_xor(sed, 16); sed += __shfl_xor(sed, 32);
    const float le = sqrtf(s2e), ld = sqrtf(s2d);
    const float sim = (sed / ((le + 1e-6f) * (ld + 1e-6f)) + 1.0f) * 0.5f;
    const float ee = __expf(le);
    if (g == 0) eexp_out[gn] = ee;
    {
        float s = ee;
        s += __shfl_xor(s, 1); s += __shfl_xor(s, 2);
        s += __shfl_xor(s, 4); s += __shfl_xor(s, 8);
        if (l == 0) redp[w] = s;
    }

    {
        f32x4 aQ[8];
#pragma unroll
        for (int ot = 0; ot < 8; ++ot) aQ[ot] = *(const f32x4*)(cq + 16 * ot + 4 * g);
#pragma unroll
        for (int ot = 0; ot < 8; ++ot)
#pragma unroll
            for (int kk = 0; kk < 4; ++kk)
                aQ[ot] = __builtin_amdgcn_mfma_f32_16x16x32_bf16(ldA(WqeB, ot, kk, l), bfrE[kk], aQ[ot], 0, 0, 0);
#pragma unroll
        for (int ot = 0; ot < 8; ++ot) {
            f32x4 b4 = *(const f32x4*)(bq + 16 * ot + 4 * g);
            u16x4 u;
#pragma unroll
            for (int r = 0; r < 4; ++r) u[r] = f2b(sim * aQ[ot][r] + b4[r]);
            *(u16x4*)(qT + gn * CC + 16 * ot + 4 * g) = u;
        }
    }
    {
        f32x4 aK[8];
#pragma unroll
        for (int ot = 0; ot < 8; ++ot) aK[ot] = *(const f32x4*)(ck + 16 * ot + 4 * g);
#pragma unroll
        for (int ot = 0; ot < 8; ++ot)
#pragma unroll
            for (int kk = 0; kk < 4; ++kk)
                aK[ot] = __builtin_amdgcn_mfma_f32_16x16x32_bf16(ldA(WkdB, ot, kk, l), bfrD[kk], aK[ot], 0, 0, 0);
#pragma unroll
        for (int ot = 0; ot < 8; ++ot) {
            u16x4 u;
#pragma unroll
            for (int r = 0; r < 4; ++r) u[r] = f2b(aK[ot][r]);
            *(u16x4*)(kT + gn * CC + 16 * ot + 4 * g) = u;
        }
    }
    {
        f32x4 aV[8];
#pragma unroll
        for (int ot = 0; ot < 8; ++ot) aV[ot] = *(const f32x4*)(cv + 16 * ot + 4 * g);
#pragma unroll
        for (int ot = 0; ot < 8; ++ot)
#pragma unroll
            for (int kk = 0; kk < 4; ++kk)
                aV[ot] = __builtin_amdgcn_mfma_f32_16x16x32_bf16(ldA(WvdB, ot, kk, l), bfrD[kk], aV[ot], 0, 0, 0);
        __syncthreads();  // bufA reads done; redp written
        if (t == 0)
            partial[(size_t)bt * 16 + (id >> 5)] = redp[0] + redp[1] + redp[2] + redp[3];
        u16* bufT = bufA; // [128][72]
#pragma unroll
        for (int ot = 0; ot < 8; ++ot)
#pragma unroll
            for (int r = 0; r < 4; ++r)
                bufT[(16 * ot + 4 * g + r) * 72 + nloc] = f2b(aV[ot][r]);
        __syncthreads();
#pragma unroll
        for (int p = 0; p < 4; ++p) {
            const int idx = t + 256 * p;
            const int c = idx >> 3, n8 = (idx & 7) * 8;
            *(u16x8*)(vN + ((size_t)bt * CC + c) * NN + n0b + n8) =
                *(const u16x8*)&bufT[c * 72 + n8];
        }
    }
}

// one kx column of QK^T -> P' -> PV (per-wave private P; within-wave fence only)
__device__ __forceinline__ void kxstep(
    int i, int qx, size_t btNN, int bt, int l15, int g,
    const u16* __restrict__ kT, const u16* __restrict__ vN,
    const float* __restrict__ eexp, float dscale,
    const float (&qbk)[2], const u16x8 (&ql)[2][4],
    float (&ssum)[2], f32x4 (&o)[8][2], u16* P)
{
    const float invsq = 0.08838834764831843f;  // 1/sqrt(128)
    const int kxr = qx - 3 + i;
    const int kxc = min(max(kxr, 0), 31);
    const bool cval = (kxr == kxc);
    f32x4 acc[2][2];
#pragma unroll
    for (int mt = 0; mt < 2; ++mt)
#pragma unroll
        for (int nt = 0; nt < 2; ++nt) acc[mt][nt] = (f32x4){0.f, 0.f, 0.f, 0.f};
#pragma unroll
    for (int kk = 0; kk < 4; ++kk)
#pragma unroll
        for (int mt = 0; mt < 2; ++mt) {
            bf16x8 ka = *(const bf16x8*)(kT + (btNN + kxc * 32 + 16 * mt + l15) * CC + 32 * kk + 8 * g);
#pragma unroll
            for (int nt = 0; nt < 2; ++nt)
                acc[mt][nt] = __builtin_amdgcn_mfma_f32_16x16x32_bf16(
                    ka, __builtin_bit_cast(bf16x8, ql[nt][kk]), acc[mt][nt], 0, 0, 0);
        }
#pragma unroll
    for (int mt = 0; mt < 2; ++mt) {
        f32x4 ee4 = *(const f32x4*)(eexp + btNN + kxc * 32 + 16 * mt + 4 * g);
        f32x4 d4;
#pragma unroll
        for (int r = 0; r < 4; ++r) d4[r] = dscale * ee4[r];
#pragma unroll
        for (int nt = 0; nt < 2; ++nt) {
            const int qyv = l15 + 16 * nt;
            u16x4 pw;
#pragma unroll
            for (int r = 0; r < 4; ++r) {
                const float s = (d4[r] * acc[mt][nt][r] + qbk[nt]) * invsq;
                const int ky = 16 * mt + 4 * g + r;
                const int dy = ky - qyv;
                const bool vld = cval && (dy >= -3) && (dy <= 3);
                const float e = vld ? __expf(s) : 0.f;
                ssum[nt] += e;
                pw[r] = f2b(e * d4[r]);
            }
            *(u16x4*)&P[qyv * PSTs + 16 * mt + 4 * g] = pw;
        }
    }
    asm volatile("s_waitcnt lgkmcnt(0)" ::: "memory");
    __builtin_amdgcn_sched_barrier(0);
    bf16x8 pb[2];
#pragma unroll
    for (int nt = 0; nt < 2; ++nt)
        pb[nt] = *(const bf16x8*)&P[(16 * nt + l15) * PSTs + 8 * g];
#pragma unroll
    for (int mt = 0; mt < 8; ++mt) {
        bf16x8 va = *(const bf16x8*)(vN + ((size_t)bt * CC + 16 * mt + l15) * NN + kxc * 32 + 8 * g);
#pragma unroll
        for (int nt = 0; nt < 2; ++nt)
            o[mt][nt] = __builtin_amdgcn_mfma_f32_16x16x32_bf16(va, pb[nt], o[mt][nt], 0, 0, 0);
    }
}

// ---------- kernel 2: FUSED attention + conv + LIF, kx-split across 2 wave-halves ----------
// block = (b, qx), 512 threads = 8 waves: (tt, h); h = kx-half. No load duplication:
// halves read disjoint kT/vN columns; merge = ssum (1KB LDS) + partial-O add (33-pad scratch).
__global__ __launch_bounds__(512) void k_attnf(
    const u16* __restrict__ qT, const u16* __restrict__ kT,
    const u16* __restrict__ vN, const float* __restrict__ eexp,
    const float* __restrict__ partial,
    const float* __restrict__ bk, const float* __restrict__ bv,
    const u16* __restrict__ WfB, const float* __restrict__ bf,
    float* __restrict__ out)
{
    __shared__ u16 lds_u16[26624];   // region A (34816 B): P / o-scratch / att
    __shared__ float convq[4 * 32 * CQS];  // 18432 B
    __shared__ float sums_l[256];    // [w][nt][l15]
    const int t = threadIdx.x;
    const int id = blockIdx.x;
    const int b = id & 7, qx = id >> 3;   // XCD x owns b = x
    const int w = t >> 6, tt = w & 3, h = w >> 2;
    const int bt = b * 4 + tt;
    const int l = t & 63, l15 = l & 15, g = l >> 4;
    u16* att = lds_u16;                       // [4][32][CPA]
    float* scratch = (float*)lds_u16;         // [4][64][SQS] f32 = 33792 B
    u16* P = lds_u16 + w * 32 * PSTs;         // 8 private buffers (20480 B)
    const size_t btNN = (size_t)bt * NN;

    // softmax denom for this bt
    float S = 0.f;
    {
        const float* pp = partial + (size_t)bt * 16;
#pragma unroll
        for (int i = 0; i < 16; ++i) S += pp[i];
    }
    const float dscale = 1024.0f / S;

    // q fragments (per wave; the only duplicated load across halves)
    u16x8 ql[2][4];
#pragma unroll
    for (int nt = 0; nt < 2; ++nt)
#pragma unroll
        for (int kk = 0; kk < 4; ++kk)
            ql[nt][kk] = *(const u16x8*)(qT + (btNN + qx * 32 + 16 * nt + l15) * CC + 32 * kk + 8 * g);

    float qbk[2] = {0.f, 0.f};
#pragma unroll
    for (int kk = 0; kk < 4; ++kk) {
        f32x4 b0 = *(const f32x4*)(bk + 32 * kk + 8 * g);
        f32x4 b1 = *(const f32x4*)(bk + 32 * kk + 8 * g + 4);
#pragma unroll
        for (int nt = 0; nt < 2; ++nt)
#pragma unroll
            for (int j = 0; j < 4; ++j) {
                qbk[nt] += b2f(ql[nt][kk][j]) * b0[j];
                qbk[nt] += b2f(ql[nt][kk][4 + j]) * b1[j];
            }
    }
#pragma unroll
    for (int nt = 0; nt < 2; ++nt) {
        qbk[nt] += __shfl_xor(qbk[nt], 16);
        qbk[nt] += __shfl_xor(qbk[nt], 32);
    }

    // ---- this wave's kx half ----
    float ssum[2] = {0.f, 0.f};
    f32x4 o[8][2];
#pragma unroll
    for (int mt = 0; mt < 8; ++mt)
#pragma unroll
        for (int nt = 0; nt < 2; ++nt) o[mt][nt] = (f32x4){0.f, 0.f, 0.f, 0.f};

    if (h == 0) {
#pragma unroll
        for (int i = 0; i < 4; ++i)
            kxstep(i, qx, btNN, bt, l15, g, kT, vN, eexp, dscale, qbk, ql, ssum, o, P);
    } else {
#pragma unroll
        for (int i = 4; i < 7; ++i)
            kxstep(i, qx, btNN, bt, l15, g, kT, vN, eexp, dscale, qbk, ql, ssum, o, P);
    }
    // reduce partial ssum across g-groups (per qy), publish to LDS
#pragma unroll
    for (int nt = 0; nt < 2; ++nt) {
        ssum[nt] += __shfl_xor(ssum[nt], 16);
        ssum[nt] += __shfl_xor(ssum[nt], 32);
        if (l < 16) sums_l[(w * 2 + nt) * 16 + l15] = ssum[nt];
    }
    __syncthreads();  // all P reads done; sums visible; region A reusable

    // ---- merge partial O: h1 -> scratch -> h0 adds (2 chunks of 64 channels) ----
#pragma unroll
    for (int c = 0; c < 2; ++c) {
        if (h == 1) {
#pragma unroll
            for (int m2 = 0; m2 < 4; ++m2)
#pragma unroll
                for (int nt = 0; nt < 2; ++nt)
#pragma unroll
                    for (int r = 0; r < 4; ++r)
                        scratch[tt * 64 * SQS + (16 * m2 + 4 * g + r) * SQS + 16 * nt + l15] =
                            o[4 * c + m2][nt][r];
        }
        __syncthreads();
        if (h == 0) {
#pragma unroll
            for (int m2 = 0; m2 < 4; ++m2)
#pragma unroll
                for (int nt = 0; nt < 2; ++nt)
#pragma unroll
                    for (int r = 0; r < 4; ++r)
                        o[4 * c + m2][nt][r] +=
                            scratch[tt * 64 * SQS + (16 * m2 + 4 * g + r) * SQS + 16 * nt + l15];
        }
        __syncthreads();
    }

    // ---- h0: total inv, att -> LDS bf16 ----
    if (h == 0) {
        float inv[2];
#pragma unroll
        for (int nt = 0; nt < 2; ++nt)
            inv[nt] = 1.0f / (ssum[nt] + sums_l[((w + 4) * 2 + nt) * 16 + l15]);
        u16* attw = att + tt * 32 * CPA;
#pragma unroll
        for (int mt = 0; mt < 8; ++mt) {
            f32x4 bv4 = *(const f32x4*)(bv + 16 * mt + 4 * g);
#pragma unroll
            for (int nt = 0; nt < 2; ++nt) {
                u16x4 ov;
#pragma unroll
                for (int r = 0; r < 4; ++r) ov[r] = f2b(o[mt][nt][r] * inv[nt] + bv4[r]);
                *(u16x4*)&attw[(16 * nt + l15) * CPA + 16 * mt + 4 * g] = ov;
            }
        }
    }
    __syncthreads();  // att ready for both halves

    // conv B-frags (both halves read own tt's att slice)
    const u16* attw = att + tt * 32 * CPA;
    bf16x8 cb[4][2];
#pragma unroll
    for (int kk = 0; kk < 4; ++kk)
#pragma unroll
        for (int nt = 0; nt < 2; ++nt)
            cb[kk][nt] = *(const bf16x8*)&attw[(16 * nt + l15) * CPA + 32 * kk + 8 * g];

    // ---- conv + LIF in 4 c-quarters; wave h owns ot = 2*cr + h ----
    const int cl = t >> 4, n2 = (t & 15) * 2;
#pragma unroll
    for (int cr = 0; cr < 4; ++cr) {
        const int ot = 2 * cr + h;
        f32x4 ca[2];
#pragma unroll
        for (int nt = 0; nt < 2; ++nt) ca[nt] = *(const f32x4*)(bf + 16 * ot + 4 * g);
#pragma unroll
        for (int kk = 0; kk < 4; ++kk) {
            bf16x8 afr = ldA(WfB, ot, kk, l);
#pragma unroll
            for (int nt = 0; nt < 2; ++nt)
                ca[nt] = __builtin_amdgcn_mfma_f32_16x16x32_bf16(afr, cb[kk][nt], ca[nt], 0, 0, 0);
        }
#pragma unroll
        for (int nt = 0; nt < 2; ++nt)
#pragma unroll
            for (int r = 0; r < 4; ++r)
                convq[tt * 32 * CQS + (16 * h + 4 * g + r) * CQS + 16 * nt + l15] = ca[nt][r];
        __syncthreads();
        // LIF over tt for c = 32*cr + cl, n = qx*32 + n2, n2+1
        float m0 = 0.f, m1 = 0.f;
#pragma unroll
        for (int tt2 = 0; tt2 < 4; ++tt2) {
            float2 x = *(const float2*)&convq[tt2 * 32 * CQS + cl * CQS + n2];
            m0 = m0 * 0.5f + x.x;
            m1 = m1 * 0.5f + x.y;
            float2 sp;
            sp.x = (m0 > 1.0f) ? 1.0f : 0.0f; if (m0 > 1.0f) m0 = 0.f;
            sp.y = (m1 > 1.0f) ? 1.0f : 0.0f; if (m1 > 1.0f) m1 = 0.f;
            *(float2*)(out + ((size_t)(b * 4 + tt2) * CC + 32 * cr + cl) * NN + qx * 32 + n2) = sp;
        }
        __syncthreads();
    }
}

extern "C" void kernel_launch(void* const* d_in, const int* in_sizes, int n_in,
                              void* d_out, int out_size, void* d_ws, size_t ws_size,
                              hipStream_t stream) {
    (void)in_sizes; (void)n_in; (void)out_size; (void)ws_size;
    const float* edge = (const float*)d_in[0];
    const float* dvs  = (const float*)d_in[1];
    const float* We = (const float*)d_in[2];
    const float* be = (const float*)d_in[3];
    const float* Wd = (const float*)d_in[4];
    const float* bd = (const float*)d_in[5];
    const float* Wq = (const float*)d_in[6];
    const float* bq = (const float*)d_in[7];
    const float* Wk = (const float*)d_in[8];
    const float* bk = (const float*)d_in[9];
    const float* Wv = (const float*)d_in[10];
    const float* bv = (const float*)d_in[11];
    const float* Wf = (const float*)d_in[12];
    const float* bf = (const float*)d_in[13];
    float* out = (float*)d_out;

    const size_t S = (size_t)BTOT * NN * CC;  // 4.19M elems
    u16* qT   = (u16*)d_ws;
    u16* kT   = qT + S;
    u16* vN   = kT + S;
    u16* WbAll = vN + S;                      // 6 * 16384 u16
    float* fbase = (float*)(WbAll + 6 * 16384);
    float* cvec  = fbase;                     // 3 * 128
    float* eexp  = cvec + 3 * CC;             // BTOT*NN
    float* partial = eexp + BTOT * NN;        // BTOT*16
    u16* WeB  = WbAll + 0 * 16384;
    u16* WdB  = WbAll + 1 * 16384;
    u16* WqeB = WbAll + 2 * 16384;
    u16* WkdB = WbAll + 3 * 16384;
    u16* WvdB = WbAll + 4 * 16384;
    u16* WfB  = WbAll + 5 * 16384;
    float* cq = cvec;
    float* ck = cvec + CC;
    float* cv = cvec + 2 * CC;

    k_prep<<<216, 256, 0, stream>>>(We, Wd, Wf, Wq, Wk, Wv, be, bd, WbAll, cvec);
    k_front<<<512, 256, 0, stream>>>(edge, dvs, WeB, WdB, WqeB, WkdB, WvdB,
                                     be, bd, bq, cq, ck, cv, eexp, partial, qT, kT, vN);
    k_attnf<<<256, 512, 0, stream>>>(qT, kT, vN, eexp, partial, bk, bv, WfB, bf, out);
}

// Round 14
// 62.232 us; speedup vs baseline: 1.1206x; 1.0293x over previous
//
#include <hip/hip_runtime.h>
#include <math.h>

#define CC 128   // channels
#define NN 1024  // H*W
#define BTOT 32  // B*T
#define CP 152   // k_front LDS row stride (bf16 elems)
#define PSTs 40  // P column-buffer row stride (u16): 80B
#define CPA 136  // q/k tile + att_lds row stride (u16): 272B = 17*16
#define CQS 36   // conv_q row stride (f32): 144B = 9*16
#define SQS 33   // o-exchange scratch row stride (f32), padded: conflict-free

typedef unsigned short u16;
typedef u16 u16x8 __attribute__((ext_vector_type(8)));
typedef u16 u16x4 __attribute__((ext_vector_type(4)));
typedef __bf16 bf16x8 __attribute__((ext_vector_type(8)));
typedef float f32x4 __attribute__((ext_vector_type(4)));

__device__ __forceinline__ u16 f2b(float f) {
    unsigned int u = __float_as_uint(f);
    u += 0x7FFFu + ((u >> 16) & 1u);   // RNE
    return (u16)(u >> 16);
}
__device__ __forceinline__ float b2f(u16 u) {
    return __uint_as_float(((unsigned int)u) << 16);
}

// ---------- MFMA helpers ----------
// A-frag: lane l holds A[16*ot + (l&15)][32*kk + 8*(l>>4) + j], j=0..7.
// B-frag: lane l holds B[16*nt + (l&15)][32*kk + 8*(l>>4) + j].
// C/D: col = l&15 (B row), row = (l>>4)*4 + r (+16*ot) (A row).
__device__ __forceinline__ void loadB(const u16* brow, int g, bf16x8 bfr[4]) {
#pragma unroll
    for (int kk = 0; kk < 4; ++kk)
        bfr[kk] = *(const bf16x8*)(brow + kk * 32 + g * 8);
}
__device__ __forceinline__ bf16x8 ldA(const u16* __restrict__ WB, int ot, int kk, int l) {
    return *(const bf16x8*)(WB + ((size_t)(ot * 4 + kk) * 64 + l) * 8);
}

// ---------- kernel 0: prep — pack We/Wd/Wf AND compose+pack Wqe/Wkd/Wvd ----------
__global__ __launch_bounds__(256) void k_prep(
    const float* __restrict__ We, const float* __restrict__ Wd,
    const float* __restrict__ Wf, const float* __restrict__ Wq,
    const float* __restrict__ Wk, const float* __restrict__ Wv,
    const float* __restrict__ be, const float* __restrict__ bd,
    u16* __restrict__ out, float* __restrict__ cvec)
{
    const int bid = blockIdx.x, t = threadIdx.x;
    if (bid < 24) {
        const int gid = bid * 256 + t;       // 0..6143
        const int wi = gid >> 11;            // 0..2
        const float* W = (wi == 0) ? We : (wi == 1) ? Wd : Wf;
        const int slot = (wi == 2) ? 5 : wi;
        const int rem = gid & 2047;
        const int ot = rem >> 8, kk = (rem >> 6) & 3, l = rem & 63;
        const int row = ot * 16 + (l & 15), col = kk * 32 + (l >> 4) * 8;
        float4 a = *(const float4*)(W + row * CC + col);
        float4 b = *(const float4*)(W + row * CC + col + 4);
        u16x8 u;
        u[0] = f2b(a.x); u[1] = f2b(a.y); u[2] = f2b(a.z); u[3] = f2b(a.w);
        u[4] = f2b(b.x); u[5] = f2b(b.y); u[6] = f2b(b.z); u[7] = f2b(b.w);
        *(u16x8*)(out + (size_t)slot * 16384 + ((size_t)(ot * 4 + kk) * 64 + l) * 8) = u;
    } else {
        const int cid = bid - 24;            // 0..191
        const int mat = cid >> 6;            // 0..2
        const int o = ((cid & 63) << 1) | (t >> 7);
        const int c = t & 127;
        const float* A = (mat == 0) ? Wq : (mat == 1) ? Wk : Wv;
        const float* B = (mat == 0) ? We : Wd;
        const float* bvec = (mat == 0) ? be : bd;
        float acc = 0.f;
        for (int m = 0; m < CC; ++m) acc += A[o * CC + m] * B[m * CC + c];
        const int ot = o >> 4, l15o = o & 15;
        const int kk = c >> 5, gc = (c >> 3) & 3, j = c & 7;
        const int l = gc * 16 + l15o;
        out[(size_t)(2 + mat) * 16384 + ((size_t)(ot * 4 + kk) * 64 + l) * 8 + j] = f2b(acc);
        if (c == 0) {
            float bacc = 0.f;
            for (int m = 0; m < CC; ++m) bacc += A[o * CC + m] * bvec[m];
            cvec[mat * CC + o] = bacc;
        }
    }
}

// ---------- kernel 1: front — 64-n tiles, XCD-aligned grid, coalesced q/k/v stores ----------
__global__ __launch_bounds__(256) void k_front(
    const float* __restrict__ edge, const float* __restrict__ dvs,
    const u16* __restrict__ WeB, const u16* __restrict__ WdB,
    const u16* __restrict__ WqeB, const u16* __restrict__ WkdB,
    const u16* __restrict__ WvdB,
    const float* __restrict__ be, const float* __restrict__ bd,
    const float* __restrict__ bq,
    const float* __restrict__ cq, const float* __restrict__ ck,
    const float* __restrict__ cv,
    float* __restrict__ eexp_out, float* __restrict__ partial,
    u16* __restrict__ qT, u16* __restrict__ kT, u16* __restrict__ vN)
{
    __shared__ u16 bufA[64 * CP];   // 19456 B
    __shared__ u16 bufB[64 * CP];   // 19456 B
    __shared__ float redp[4];
    const int t = threadIdx.x;
    const int id = blockIdx.x;
    const int bt = (id & 7) * 4 + ((id >> 3) & 3);
    const int n0b = (id >> 5) * 64;
    const float* eb = edge + (size_t)bt * CC * NN + n0b;
    const float* db = dvs + (size_t)bt * CC * NN + n0b;

    // stage: transpose [c][n] fp32 -> [n][c] bf16
#pragma unroll
    for (int j = 0; j < 2; ++j) {
        const int i = t + 256 * j;
        const int c4 = i >> 4, p = i & 15;
        float4 e[4], d[4];
#pragma unroll
        for (int m = 0; m < 4; ++m) {
            e[m] = *(const float4*)(eb + (size_t)(4 * c4 + m) * NN + 4 * p);
            d[m] = *(const float4*)(db + (size_t)(4 * c4 + m) * NN + 4 * p);
        }
#pragma unroll
        for (int n = 0; n < 4; ++n) {
            u16x4 ue, ud;
            ue[0] = f2b(((const float*)&e[0])[n]); ud[0] = f2b(((const float*)&d[0])[n]);
            ue[1] = f2b(((const float*)&e[1])[n]); ud[1] = f2b(((const float*)&d[1])[n]);
            ue[2] = f2b(((const float*)&e[2])[n]); ud[2] = f2b(((const float*)&d[2])[n]);
            ue[3] = f2b(((const float*)&e[3])[n]); ud[3] = f2b(((const float*)&d[3])[n]);
            *(u16x4*)&bufA[(4 * p + n) * CP + 4 * c4] = ue;
            *(u16x4*)&bufB[(4 * p + n) * CP + 4 * c4] = ud;
        }
    }
    __syncthreads();

    const int w = t >> 6, l = t & 63;
    const int l15 = l & 15, g = l >> 4;
    const int nloc = w * 16 + l15;
    const size_t gn = (size_t)bt * NN + n0b + nloc;
    const size_t rowbase = (size_t)bt * NN + n0b;

    bf16x8 bfrE[4], bfrD[4];
    loadB(bufA + nloc * CP, g, bfrE);
    loadB(bufB + nloc * CP, g, bfrD);

    // --- ef/df accumulators (stats only, never materialized) ---
    f32x4 aE[8], aD[8];
#pragma unroll
    for (int ot = 0; ot < 8; ++ot) {
        aE[ot] = *(const f32x4*)(be + 16 * ot + 4 * g);
        aD[ot] = *(const f32x4*)(bd + 16 * ot + 4 * g);
    }
#pragma unroll
    for (int ot = 0; ot < 8; ++ot)
#pragma unroll
        for (int kk = 0; kk < 4; ++kk) {
            aE[ot] = __builtin_amdgcn_mfma_f32_16x16x32_bf16(ldA(WeB, ot, kk, l), bfrE[kk], aE[ot], 0, 0, 0);
            aD[ot] = __builtin_amdgcn_mfma_f32_16x16x32_bf16(ldA(WdB, ot, kk, l), bfrD[kk], aD[ot], 0, 0, 0);
        }
    float s2e = 0.f, s2d = 0.f, sed = 0.f;
#pragma unroll
    for (int ot = 0; ot < 8; ++ot)
#pragma unroll
        for (int r = 0; r < 4; ++r) {
            const float fe = aE[ot][r], fd = aD[ot][r];
            s2e += fe * fe; s2d += fd * fd; sed += fe * fd;
        }
    s2e += __shfl_xor(s2e, 16); s2e += __shfl_xor(s2e, 32);
    s2d += __shfl_xor(s2d, 16); s2d += __shfl_xor(s2d, 32);
    sed += __shfl_xor(sed, 16); sed += __shfl_xor(sed, 32);
    const float le = sqrtf(s2e), ld = sqrtf(s2d);
    const float sim = (sed / ((le + 1e-6f) * (ld + 1e-6f)) + 1.0f) * 0.5f;
    const float ee = __expf(le);
    if (g == 0) eexp_out[gn] = ee;
    {
        float s = ee;
        s += __shfl_xor(s, 1); s += __shfl_xor(s, 2);
        s += __shfl_xor(s, 4); s += __shfl_xor(s, 8);
        if (l == 0) redp[w] = s;
    }

    __syncthreads();  // (1) all frag reads + redp done -> bufA/bufB reusable
    if (t == 0)
        partial[(size_t)bt * 16 + (id >> 5)] = redp[0] + redp[1] + redp[2] + redp[3];

    // --- q = sim*(Wqe*e + cq) + bq  -> bufA[n][CPA] ---
    {
        f32x4 aQ[8];
#pragma unroll
        for (int ot = 0; ot < 8; ++ot) aQ[ot] = *(const f32x4*)(cq + 16 * ot + 4 * g);
#pragma unroll
        for (int ot = 0; ot < 8; ++ot)
#pragma unroll
            for (int kk = 0; kk < 4; ++kk)
                aQ[ot] = __builtin_amdgcn_mfma_f32_16x16x32_bf16(ldA(WqeB, ot, kk, l), bfrE[kk], aQ[ot], 0, 0, 0);
#pragma unroll
        for (int ot = 0; ot < 8; ++ot) {
            f32x4 b4 = *(const f32x4*)(bq + 16 * ot + 4 * g);
            u16x4 u;
#pragma unroll
            for (int r = 0; r < 4; ++r) u[r] = f2b(sim * aQ[ot][r] + b4[r]);
            *(u16x4*)&bufA[nloc * CPA + 16 * ot + 4 * g] = u;
        }
    }
    // --- kraw = Wkd*d + ck -> bufB[n][CPA] ---
    {
        f32x4 aK[8];
#pragma unroll
        for (int ot = 0; ot < 8; ++ot) aK[ot] = *(const f32x4*)(ck + 16 * ot + 4 * g);
#pragma unroll
        for (int ot = 0; ot < 8; ++ot)
#pragma unroll
            for (int kk = 0; kk < 4; ++kk)
                aK[ot] = __builtin_amdgcn_mfma_f32_16x16x32_bf16(ldA(WkdB, ot, kk, l), bfrD[kk], aK[ot], 0, 0, 0);
#pragma unroll
        for (int ot = 0; ot < 8; ++ot) {
            u16x4 u;
#pragma unroll
            for (int r = 0; r < 4; ++r) u[r] = f2b(aK[ot][r]);
            *(u16x4*)&bufB[nloc * CPA + 16 * ot + 4 * g] = u;
        }
    }
    __syncthreads();  // (2) q/k tiles complete
    // coalesced copy-out: 64 rows x 16 segs of u16x8
#pragma unroll
    for (int p = 0; p < 4; ++p) {
        const int idx = t + 256 * p;
        const int row = idx >> 4, seg = idx & 15;
        *(u16x8*)(qT + (rowbase + row) * CC + seg * 8) = *(const u16x8*)&bufA[row * CPA + seg * 8];
        *(u16x8*)(kT + (rowbase + row) * CC + seg * 8) = *(const u16x8*)&bufB[row * CPA + seg * 8];
    }

    // --- vraw = Wvd*d + cv ; channel-major vN[c][n] via LDS transpose ---
    {
        f32x4 aV[8];
#pragma unroll
        for (int ot = 0; ot < 8; ++ot) aV[ot] = *(const f32x4*)(cv + 16 * ot + 4 * g);
#pragma unroll
        for (int ot = 0; ot < 8; ++ot)
#pragma unroll
            for (int kk = 0; kk < 4; ++kk)
                aV[ot] = __builtin_amdgcn_mfma_f32_16x16x32_bf16(ldA(WvdB, ot, kk, l), bfrD[kk], aV[ot], 0, 0, 0);
        __syncthreads();  // (3) q/k copies done reading bufA/bufB
        u16* bufT = bufA; // [128][72] u16 = 18432 B <= bufA
#pragma unroll
        for (int ot = 0; ot < 8; ++ot)
#pragma unroll
            for (int r = 0; r < 4; ++r)
                bufT[(16 * ot + 4 * g + r) * 72 + nloc] = f2b(aV[ot][r]);
        __syncthreads();  // (4)
#pragma unroll
        for (int p = 0; p < 4; ++p) {
            const int idx = t + 256 * p;
            const int c = idx >> 3, n8 = (idx & 7) * 8;
            *(u16x8*)(vN + ((size_t)bt * CC + c) * NN + n0b + n8) =
                *(const u16x8*)&bufT[c * 72 + n8];
        }
    }
}

// one kx column of QK^T -> P' -> PV (per-wave private P; within-wave fence only)
__device__ __forceinline__ void kxstep(
    int i, int qx, size_t btNN, int bt, int l15, int g,
    const u16* __restrict__ kT, const u16* __restrict__ vN,
    const float* __restrict__ eexp, float dscale,
    const float (&qbk)[2], const u16x8 (&ql)[2][4],
    float (&ssum)[2], f32x4 (&o)[8][2], u16* P)
{
    const float invsq = 0.08838834764831843f;  // 1/sqrt(128)
    const int kxr = qx - 3 + i;
    const int kxc = min(max(kxr, 0), 31);
    const bool cval = (kxr == kxc);
    f32x4 acc[2][2];
#pragma unroll
    for (int mt = 0; mt < 2; ++mt)
#pragma unroll
        for (int nt = 0; nt < 2; ++nt) acc[mt][nt] = (f32x4){0.f, 0.f, 0.f, 0.f};
#pragma unroll
    for (int kk = 0; kk < 4; ++kk)
#pragma unroll
        for (int mt = 0; mt < 2; ++mt) {
            bf16x8 ka = *(const bf16x8*)(kT + (btNN + kxc * 32 + 16 * mt + l15) * CC + 32 * kk + 8 * g);
#pragma unroll
            for (int nt = 0; nt < 2; ++nt)
                acc[mt][nt] = __builtin_amdgcn_mfma_f32_16x16x32_bf16(
                    ka, __builtin_bit_cast(bf16x8, ql[nt][kk]), acc[mt][nt], 0, 0, 0);
        }
#pragma unroll
    for (int mt = 0; mt < 2; ++mt) {
        f32x4 ee4 = *(const f32x4*)(eexp + btNN + kxc * 32 + 16 * mt + 4 * g);
        f32x4 d4;
#pragma unroll
        for (int r = 0; r < 4; ++r) d4[r] = dscale * ee4[r];
#pragma unroll
        for (int nt = 0; nt < 2; ++nt) {
            const int qyv = l15 + 16 * nt;
            u16x4 pw;
#pragma unroll
            for (int r = 0; r < 4; ++r) {
                const float s = (d4[r] * acc[mt][nt][r] + qbk[nt]) * invsq;
                const int ky = 16 * mt + 4 * g + r;
                const int dy = ky - qyv;
                const bool vld = cval && (dy >= -3) && (dy <= 3);
                const float e = vld ? __expf(s) : 0.f;
                ssum[nt] += e;
                pw[r] = f2b(e * d4[r]);
            }
            *(u16x4*)&P[qyv * PSTs + 16 * mt + 4 * g] = pw;
        }
    }
    asm volatile("s_waitcnt lgkmcnt(0)" ::: "memory");
    __builtin_amdgcn_sched_barrier(0);
    bf16x8 pb[2];
#pragma unroll
    for (int nt = 0; nt < 2; ++nt)
        pb[nt] = *(const bf16x8*)&P[(16 * nt + l15) * PSTs + 8 * g];
#pragma unroll
    for (int mt = 0; mt < 8; ++mt) {
        bf16x8 va = *(const bf16x8*)(vN + ((size_t)bt * CC + 16 * mt + l15) * NN + kxc * 32 + 8 * g);
#pragma unroll
        for (int nt = 0; nt < 2; ++nt)
            o[mt][nt] = __builtin_amdgcn_mfma_f32_16x16x32_bf16(va, pb[nt], o[mt][nt], 0, 0, 0);
    }
}

// ---------- kernel 2: FUSED attention + conv + LIF, kx-split across 2 wave-halves ----------
__global__ __launch_bounds__(512) void k_attnf(
    const u16* __restrict__ qT, const u16* __restrict__ kT,
    const u16* __restrict__ vN, const float* __restrict__ eexp,
    const float* __restrict__ partial,
    const float* __restrict__ bk, const float* __restrict__ bv,
    const u16* __restrict__ WfB, const float* __restrict__ bf,
    float* __restrict__ out)
{
    __shared__ u16 lds_u16[26624];   // region A (34816 B): P / o-scratch / att
    __shared__ float convq[4 * 32 * CQS];  // 18432 B
    __shared__ float sums_l[256];    // [w][nt][l15]
    const int t = threadIdx.x;
    const int id = blockIdx.x;
    const int b = id & 7, qx = id >> 3;   // XCD x owns b = x
    const int w = t >> 6, tt = w & 3, h = w >> 2;
    const int bt = b * 4 + tt;
    const int l = t & 63, l15 = l & 15, g = l >> 4;
    u16* att = lds_u16;                       // [4][32][CPA]
    float* scratch = (float*)lds_u16;         // [4][64][SQS] f32 = 33792 B
    u16* P = lds_u16 + w * 32 * PSTs;         // 8 private buffers (20480 B)
    const size_t btNN = (size_t)bt * NN;

    float S = 0.f;
    {
        const float* pp = partial + (size_t)bt * 16;
#pragma unroll
        for (int i = 0; i < 16; ++i) S += pp[i];
    }
    const float dscale = 1024.0f / S;

    u16x8 ql[2][4];
#pragma unroll
    for (int nt = 0; nt < 2; ++nt)
#pragma unroll
        for (int kk = 0; kk < 4; ++kk)
            ql[nt][kk] = *(const u16x8*)(qT + (btNN + qx * 32 + 16 * nt + l15) * CC + 32 * kk + 8 * g);

    float qbk[2] = {0.f, 0.f};
#pragma unroll
    for (int kk = 0; kk < 4; ++kk) {
        f32x4 b0 = *(const f32x4*)(bk + 32 * kk + 8 * g);
        f32x4 b1 = *(const f32x4*)(bk + 32 * kk + 8 * g + 4);
#pragma unroll
        for (int nt = 0; nt < 2; ++nt)
#pragma unroll
            for (int j = 0; j < 4; ++j) {
                qbk[nt] += b2f(ql[nt][kk][j]) * b0[j];
                qbk[nt] += b2f(ql[nt][kk][4 + j]) * b1[j];
            }
    }
#pragma unroll
    for (int nt = 0; nt < 2; ++nt) {
        qbk[nt] += __shfl_xor(qbk[nt], 16);
        qbk[nt] += __shfl_xor(qbk[nt], 32);
    }

    float ssum[2] = {0.f, 0.f};
    f32x4 o[8][2];
#pragma unroll
    for (int mt = 0; mt < 8; ++mt)
#pragma unroll
        for (int nt = 0; nt < 2; ++nt) o[mt][nt] = (f32x4){0.f, 0.f, 0.f, 0.f};

    if (h == 0) {
#pragma unroll
        for (int i = 0; i < 4; ++i)
            kxstep(i, qx, btNN, bt, l15, g, kT, vN, eexp, dscale, qbk, ql, ssum, o, P);
    } else {
#pragma unroll
        for (int i = 4; i < 7; ++i)
            kxstep(i, qx, btNN, bt, l15, g, kT, vN, eexp, dscale, qbk, ql, ssum, o, P);
    }
#pragma unroll
    for (int nt = 0; nt < 2; ++nt) {
        ssum[nt] += __shfl_xor(ssum[nt], 16);
        ssum[nt] += __shfl_xor(ssum[nt], 32);
        if (l < 16) sums_l[(w * 2 + nt) * 16 + l15] = ssum[nt];
    }
    __syncthreads();  // all P reads done; sums visible; region A reusable

#pragma unroll
    for (int c = 0; c < 2; ++c) {
        if (h == 1) {
#pragma unroll
            for (int m2 = 0; m2 < 4; ++m2)
#pragma unroll
                for (int nt = 0; nt < 2; ++nt)
#pragma unroll
                    for (int r = 0; r < 4; ++r)
                        scratch[tt * 64 * SQS + (16 * m2 + 4 * g + r) * SQS + 16 * nt + l15] =
                            o[4 * c + m2][nt][r];
        }
        __syncthreads();
        if (h == 0) {
#pragma unroll
            for (int m2 = 0; m2 < 4; ++m2)
#pragma unroll
                for (int nt = 0; nt < 2; ++nt)
#pragma unroll
                    for (int r = 0; r < 4; ++r)
                        o[4 * c + m2][nt][r] +=
                            scratch[tt * 64 * SQS + (16 * m2 + 4 * g + r) * SQS + 16 * nt + l15];
        }
        __syncthreads();
    }

    if (h == 0) {
        float inv[2];
#pragma unroll
        for (int nt = 0; nt < 2; ++nt)
            inv[nt] = 1.0f / (ssum[nt] + sums_l[((w + 4) * 2 + nt) * 16 + l15]);
        u16* attw = att + tt * 32 * CPA;
#pragma unroll
        for (int mt = 0; mt < 8; ++mt) {
            f32x4 bv4 = *(const f32x4*)(bv + 16 * mt + 4 * g);
#pragma unroll
            for (int nt = 0; nt < 2; ++nt) {
                u16x4 ov;
#pragma unroll
                for (int r = 0; r < 4; ++r) ov[r] = f2b(o[mt][nt][r] * inv[nt] + bv4[r]);
                *(u16x4*)&attw[(16 * nt + l15) * CPA + 16 * mt + 4 * g] = ov;
            }
        }
    }
    __syncthreads();  // att ready for both halves

    const u16* attw = att + tt * 32 * CPA;
    bf16x8 cb[4][2];
#pragma unroll
    for (int kk = 0; kk < 4; ++kk)
#pragma unroll
        for (int nt = 0; nt < 2; ++nt)
            cb[kk][nt] = *(const bf16x8*)&attw[(16 * nt + l15) * CPA + 32 * kk + 8 * g];

    const int cl = t >> 4, n2 = (t & 15) * 2;
#pragma unroll
    for (int cr = 0; cr < 4; ++cr) {
        const int ot = 2 * cr + h;
        f32x4 ca[2];
#pragma unroll
        for (int nt = 0; nt < 2; ++nt) ca[nt] = *(const f32x4*)(bf + 16 * ot + 4 * g);
#pragma unroll
        for (int kk = 0; kk < 4; ++kk) {
            bf16x8 afr = ldA(WfB, ot, kk, l);
#pragma unroll
            for (int nt = 0; nt < 2; ++nt)
                ca[nt] = __builtin_amdgcn_mfma_f32_16x16x32_bf16(afr, cb[kk][nt], ca[nt], 0, 0, 0);
        }
#pragma unroll
        for (int nt = 0; nt < 2; ++nt)
#pragma unroll
            for (int r = 0; r < 4; ++r)
                convq[tt * 32 * CQS + (16 * h + 4 * g + r) * CQS + 16 * nt + l15] = ca[nt][r];
        __syncthreads();
        float m0 = 0.f, m1 = 0.f;
#pragma unroll
        for (int tt2 = 0; tt2 < 4; ++tt2) {
            float2 x = *(const float2*)&convq[tt2 * 32 * CQS + cl * CQS + n2];
            m0 = m0 * 0.5f + x.x;
            m1 = m1 * 0.5f + x.y;
            float2 sp;
            sp.x = (m0 > 1.0f) ? 1.0f : 0.0f; if (m0 > 1.0f) m0 = 0.f;
            sp.y = (m1 > 1.0f) ? 1.0f : 0.0f; if (m1 > 1.0f) m1 = 0.f;
            *(float2*)(out + ((size_t)(b * 4 + tt2) * CC + 32 * cr + cl) * NN + qx * 32 + n2) = sp;
        }
        __syncthreads();
    }
}

extern "C" void kernel_launch(void* const* d_in, const int* in_sizes, int n_in,
                              void* d_out, int out_size, void* d_ws, size_t ws_size,
                              hipStream_t stream) {
    (void)in_sizes; (void)n_in; (void)out_size; (void)ws_size;
    const float* edge = (const float*)d_in[0];
    const float* dvs  = (const float*)d_in[1];
    const float* We = (const float*)d_in[2];
    const float* be = (const float*)d_in[3];
    const float* Wd = (const float*)d_in[4];
    const float* bd = (const float*)d_in[5];
    const float* Wq = (const float*)d_in[6];
    const float* bq = (const float*)d_in[7];
    const float* Wk = (const float*)d_in[8];
    const float* bk = (const float*)d_in[9];
    const float* Wv = (const float*)d_in[10];
    const float* bv = (const float*)d_in[11];
    const float* Wf = (const float*)d_in[12];
    const float* bf = (const float*)d_in[13];
    float* out = (float*)d_out;

    const size_t S = (size_t)BTOT * NN * CC;  // 4.19M elems
    u16* qT   = (u16*)d_ws;
    u16* kT   = qT + S;
    u16* vN   = kT + S;
    u16* WbAll = vN + S;                      // 6 * 16384 u16
    float* fbase = (float*)(WbAll + 6 * 16384);
    float* cvec  = fbase;                     // 3 * 128
    float* eexp  = cvec + 3 * CC;             // BTOT*NN
    float* partial = eexp + BTOT * NN;        // BTOT*16
    u16* WeB  = WbAll + 0 * 16384;
    u16* WdB  = WbAll + 1 * 16384;
    u16* WqeB = WbAll + 2 * 16384;
    u16* WkdB = WbAll + 3 * 16384;
    u16* WvdB = WbAll + 4 * 16384;
    u16* WfB  = WbAll + 5 * 16384;
    float* cq = cvec;
    float* ck = cvec + CC;
    float* cv = cvec + 2 * CC;

    k_prep<<<216, 256, 0, stream>>>(We, Wd, Wf, Wq, Wk, Wv, be, bd, WbAll, cvec);
    k_front<<<512, 256, 0, stream>>>(edge, dvs, WeB, WdB, WqeB, WkdB, WvdB,
                                     be, bd, bq, cq, ck, cv, eexp, partial, qT, kT, vN);
    k_attnf<<<256, 512, 0, stream>>>(qT, kT, vN, eexp, partial, bk, bv, WfB, bf, out);
}

// Round 15
// 56.954 us; speedup vs baseline: 1.2244x; 1.0927x over previous
//
#include <hip/hip_runtime.h>
#include <math.h>

#define CC 128   // channels
#define NN 1024  // H*W
#define BTOT 32  // B*T
#define CP 152   // k_front LDS row stride (bf16 elems)
#define PSTs 40  // P column-buffer row stride (u16): 80B
#define CPA 136  // q/k tile + att_lds row stride (u16): 272B = 17*16
#define CQS 36   // conv_q row stride (f32): 144B = 9*16
#define SQS 33   // o-exchange scratch row stride (f32), padded: conflict-free

typedef unsigned short u16;
typedef u16 u16x8 __attribute__((ext_vector_type(8)));
typedef u16 u16x4 __attribute__((ext_vector_type(4)));
typedef __bf16 bf16x8 __attribute__((ext_vector_type(8)));
typedef float f32x4 __attribute__((ext_vector_type(4)));

__device__ __forceinline__ u16 f2b(float f) {
    unsigned int u = __float_as_uint(f);
    u += 0x7FFFu + ((u >> 16) & 1u);   // RNE
    return (u16)(u >> 16);
}
__device__ __forceinline__ float b2f(u16 u) {
    return __uint_as_float(((unsigned int)u) << 16);
}

// ---------- MFMA helpers ----------
// A-frag: lane l holds A[16*ot + (l&15)][32*kk + 8*(l>>4) + j], j=0..7.
// B-frag: lane l holds B[16*nt + (l&15)][32*kk + 8*(l>>4) + j].
// C/D: col = l&15 (B row), row = (l>>4)*4 + r (+16*ot) (A row).
__device__ __forceinline__ void loadB(const u16* brow, int g, bf16x8 bfr[4]) {
#pragma unroll
    for (int kk = 0; kk < 4; ++kk)
        bfr[kk] = *(const bf16x8*)(brow + kk * 32 + g * 8);
}
__device__ __forceinline__ bf16x8 ldA(const u16* WB, int ot, int kk, int l) {
    return *(const bf16x8*)(WB + ((size_t)(ot * 4 + kk) * 64 + l) * 8);
}
// stage one packed 32KB weight matrix global -> LDS (256 threads)
__device__ __forceinline__ void stageW(const u16* __restrict__ src, u16* dst, int t) {
#pragma unroll
    for (int p = 0; p < 8; ++p) {
        const int idx = t + 256 * p;
        *(u16x8*)(dst + idx * 8) = *(const u16x8*)(src + idx * 8);
    }
}

// ---------- kernel 0: prep — pack We/Wd/Wf AND compose+pack Wqe/Wkd/Wvd ----------
__global__ __launch_bounds__(256) void k_prep(
    const float* __restrict__ We, const float* __restrict__ Wd,
    const float* __restrict__ Wf, const float* __restrict__ Wq,
    const float* __restrict__ Wk, const float* __restrict__ Wv,
    const float* __restrict__ be, const float* __restrict__ bd,
    u16* __restrict__ out, float* __restrict__ cvec)
{
    const int bid = blockIdx.x, t = threadIdx.x;
    if (bid < 24) {
        const int gid = bid * 256 + t;       // 0..6143
        const int wi = gid >> 11;            // 0..2
        const float* W = (wi == 0) ? We : (wi == 1) ? Wd : Wf;
        const int slot = (wi == 2) ? 5 : wi;
        const int rem = gid & 2047;
        const int ot = rem >> 8, kk = (rem >> 6) & 3, l = rem & 63;
        const int row = ot * 16 + (l & 15), col = kk * 32 + (l >> 4) * 8;
        float4 a = *(const float4*)(W + row * CC + col);
        float4 b = *(const float4*)(W + row * CC + col + 4);
        u16x8 u;
        u[0] = f2b(a.x); u[1] = f2b(a.y); u[2] = f2b(a.z); u[3] = f2b(a.w);
        u[4] = f2b(b.x); u[5] = f2b(b.y); u[6] = f2b(b.z); u[7] = f2b(b.w);
        *(u16x8*)(out + (size_t)slot * 16384 + ((size_t)(ot * 4 + kk) * 64 + l) * 8) = u;
    } else {
        const int cid = bid - 24;            // 0..191
        const int mat = cid >> 6;            // 0..2
        const int o = ((cid & 63) << 1) | (t >> 7);
        const int c = t & 127;
        const float* A = (mat == 0) ? Wq : (mat == 1) ? Wk : Wv;
        const float* B = (mat == 0) ? We : Wd;
        const float* bvec = (mat == 0) ? be : bd;
        float acc = 0.f;
        for (int m = 0; m < CC; ++m) acc += A[o * CC + m] * B[m * CC + c];
        const int ot = o >> 4, l15o = o & 15;
        const int kk = c >> 5, gc = (c >> 3) & 3, j = c & 7;
        const int l = gc * 16 + l15o;
        out[(size_t)(2 + mat) * 16384 + ((size_t)(ot * 4 + kk) * 64 + l) * 8 + j] = f2b(acc);
        if (c == 0) {
            float bacc = 0.f;
            for (int m = 0; m < CC; ++m) bacc += A[o * CC + m] * bvec[m];
            cvec[mat * CC + o] = bacc;
        }
    }
}

// ---------- kernel 1: front — 64-n tiles, XCD-aligned grid, LDS-staged weights ----------
__global__ __launch_bounds__(256) void k_front(
    const float* __restrict__ edge, const float* __restrict__ dvs,
    const u16* __restrict__ WeB, const u16* __restrict__ WdB,
    const u16* __restrict__ WqeB, const u16* __restrict__ WkdB,
    const u16* __restrict__ WvdB,
    const float* __restrict__ be, const float* __restrict__ bd,
    const float* __restrict__ bq,
    const float* __restrict__ cq, const float* __restrict__ ck,
    const float* __restrict__ cv,
    float* __restrict__ eexp_out, float* __restrict__ partial,
    u16* __restrict__ qT, u16* __restrict__ kT, u16* __restrict__ vN)
{
    __shared__ u16 bufA[64 * CP];   // 19456 B
    __shared__ u16 bufB[64 * CP];   // 19456 B
    __shared__ u16 wbuf[16384];     // 32768 B — one packed weight matrix
    __shared__ float redp[4];
    const int t = threadIdx.x;
    const int id = blockIdx.x;
    const int bt = (id & 7) * 4 + ((id >> 3) & 3);
    const int n0b = (id >> 5) * 64;
    const float* eb = edge + (size_t)bt * CC * NN + n0b;
    const float* db = dvs + (size_t)bt * CC * NN + n0b;

    // stage inputs: transpose [c][n] fp32 -> [n][c] bf16 (+ We weights to wbuf)
#pragma unroll
    for (int j = 0; j < 2; ++j) {
        const int i = t + 256 * j;
        const int c4 = i >> 4, p = i & 15;
        float4 e[4], d[4];
#pragma unroll
        for (int m = 0; m < 4; ++m) {
            e[m] = *(const float4*)(eb + (size_t)(4 * c4 + m) * NN + 4 * p);
            d[m] = *(const float4*)(db + (size_t)(4 * c4 + m) * NN + 4 * p);
        }
#pragma unroll
        for (int n = 0; n < 4; ++n) {
            u16x4 ue, ud;
            ue[0] = f2b(((const float*)&e[0])[n]); ud[0] = f2b(((const float*)&d[0])[n]);
            ue[1] = f2b(((const float*)&e[1])[n]); ud[1] = f2b(((const float*)&d[1])[n]);
            ue[2] = f2b(((const float*)&e[2])[n]); ud[2] = f2b(((const float*)&d[2])[n]);
            ue[3] = f2b(((const float*)&e[3])[n]); ud[3] = f2b(((const float*)&d[3])[n]);
            *(u16x4*)&bufA[(4 * p + n) * CP + 4 * c4] = ue;
            *(u16x4*)&bufB[(4 * p + n) * CP + 4 * c4] = ud;
        }
    }
    stageW(WeB, wbuf, t);
    __syncthreads();   // (1) inputs + We staged

    const int w = t >> 6, l = t & 63;
    const int l15 = l & 15, g = l >> 4;
    const int nloc = w * 16 + l15;
    const size_t gn = (size_t)bt * NN + n0b + nloc;
    const size_t rowbase = (size_t)bt * NN + n0b;

    bf16x8 bfrE[4], bfrD[4];
    loadB(bufA + nloc * CP, g, bfrE);
    loadB(bufB + nloc * CP, g, bfrD);

    // --- ef accumulator (stats only) from LDS weights ---
    f32x4 aE[8], aD[8];
#pragma unroll
    for (int ot = 0; ot < 8; ++ot) aE[ot] = *(const f32x4*)(be + 16 * ot + 4 * g);
#pragma unroll
    for (int ot = 0; ot < 8; ++ot)
#pragma unroll
        for (int kk = 0; kk < 4; ++kk)
            aE[ot] = __builtin_amdgcn_mfma_f32_16x16x32_bf16(ldA(wbuf, ot, kk, l), bfrE[kk], aE[ot], 0, 0, 0);
    __syncthreads();   // (2) We reads done
    stageW(WdB, wbuf, t);
    __syncthreads();   // (3) Wd staged
#pragma unroll
    for (int ot = 0; ot < 8; ++ot) aD[ot] = *(const f32x4*)(bd + 16 * ot + 4 * g);
#pragma unroll
    for (int ot = 0; ot < 8; ++ot)
#pragma unroll
        for (int kk = 0; kk < 4; ++kk)
            aD[ot] = __builtin_amdgcn_mfma_f32_16x16x32_bf16(ldA(wbuf, ot, kk, l), bfrD[kk], aD[ot], 0, 0, 0);

    float s2e = 0.f, s2d = 0.f, sed = 0.f;
#pragma unroll
    for (int ot = 0; ot < 8; ++ot)
#pragma unroll
        for (int r = 0; r < 4; ++r) {
            const float fe = aE[ot][r], fd = aD[ot][r];
            s2e += fe * fe; s2d += fd * fd; sed += fe * fd;
        }
    s2e += __shfl_xor(s2e, 16); s2e += __shfl_xor(s2e, 32);
    s2d += __shfl_xor(s2d, 16); s2d += __shfl_xor(s2d, 32);
    sed += __shfl_xor(sed, 16); sed += __shfl_xor(sed, 32);
    const float le = sqrtf(s2e), ld = sqrtf(s2d);
    const float sim = (sed / ((le + 1e-6f) * (ld + 1e-6f)) + 1.0f) * 0.5f;
    const float ee = __expf(le);
    if (g == 0) eexp_out[gn] = ee;
    {
        float s = ee;
        s += __shfl_xor(s, 1); s += __shfl_xor(s, 2);
        s += __shfl_xor(s, 4); s += __shfl_xor(s, 8);
        if (l == 0) redp[w] = s;
    }

    __syncthreads();   // (4) Wd reads + redp done; bufA/bufB frag reads done
    stageW(WqeB, wbuf, t);
    __syncthreads();   // (5) Wqe staged
    if (t == 0)
        partial[(size_t)bt * 16 + (id >> 5)] = redp[0] + redp[1] + redp[2] + redp[3];

    // --- q = sim*(Wqe*e + cq) + bq -> bufA[n][CPA] ---
    {
        f32x4 aQ[8];
#pragma unroll
        for (int ot = 0; ot < 8; ++ot) aQ[ot] = *(const f32x4*)(cq + 16 * ot + 4 * g);
#pragma unroll
        for (int ot = 0; ot < 8; ++ot)
#pragma unroll
            for (int kk = 0; kk < 4; ++kk)
                aQ[ot] = __builtin_amdgcn_mfma_f32_16x16x32_bf16(ldA(wbuf, ot, kk, l), bfrE[kk], aQ[ot], 0, 0, 0);
#pragma unroll
        for (int ot = 0; ot < 8; ++ot) {
            f32x4 b4 = *(const f32x4*)(bq + 16 * ot + 4 * g);
            u16x4 u;
#pragma unroll
            for (int r = 0; r < 4; ++r) u[r] = f2b(sim * aQ[ot][r] + b4[r]);
            *(u16x4*)&bufA[nloc * CPA + 16 * ot + 4 * g] = u;
        }
    }
    __syncthreads();   // (6) Wqe reads done
    stageW(WkdB, wbuf, t);
    __syncthreads();   // (7) Wkd staged
    // --- kraw = Wkd*d + ck -> bufB[n][CPA] ---
    {
        f32x4 aK[8];
#pragma unroll
        for (int ot = 0; ot < 8; ++ot) aK[ot] = *(const f32x4*)(ck + 16 * ot + 4 * g);
#pragma unroll
        for (int ot = 0; ot < 8; ++ot)
#pragma unroll
            for (int kk = 0; kk < 4; ++kk)
                aK[ot] = __builtin_amdgcn_mfma_f32_16x16x32_bf16(ldA(wbuf, ot, kk, l), bfrD[kk], aK[ot], 0, 0, 0);
#pragma unroll
        for (int ot = 0; ot < 8; ++ot) {
            u16x4 u;
#pragma unroll
            for (int r = 0; r < 4; ++r) u[r] = f2b(aK[ot][r]);
            *(u16x4*)&bufB[nloc * CPA + 16 * ot + 4 * g] = u;
        }
    }
    __syncthreads();   // (8) q/k tiles complete; Wkd reads done
    stageW(WvdB, wbuf, t);   // overlaps with q/k copy-out
    // coalesced copy-out: 64 rows x 16 segs of u16x8
#pragma unroll
    for (int p = 0; p < 4; ++p) {
        const int idx = t + 256 * p;
        const int row = idx >> 4, seg = idx & 15;
        *(u16x8*)(qT + (rowbase + row) * CC + seg * 8) = *(const u16x8*)&bufA[row * CPA + seg * 8];
        *(u16x8*)(kT + (rowbase + row) * CC + seg * 8) = *(const u16x8*)&bufB[row * CPA + seg * 8];
    }
    __syncthreads();   // (9) Wvd staged; copy-out LDS reads done

    // --- vraw = Wvd*d + cv ; channel-major vN[c][n] via LDS transpose ---
    {
        f32x4 aV[8];
#pragma unroll
        for (int ot = 0; ot < 8; ++ot) aV[ot] = *(const f32x4*)(cv + 16 * ot + 4 * g);
#pragma unroll
        for (int ot = 0; ot < 8; ++ot)
#pragma unroll
            for (int kk = 0; kk < 4; ++kk)
                aV[ot] = __builtin_amdgcn_mfma_f32_16x16x32_bf16(ldA(wbuf, ot, kk, l), bfrD[kk], aV[ot], 0, 0, 0);
        u16* bufT = bufA; // [128][72] u16 = 18432 B
#pragma unroll
        for (int ot = 0; ot < 8; ++ot)
#pragma unroll
            for (int r = 0; r < 4; ++r)
                bufT[(16 * ot + 4 * g + r) * 72 + nloc] = f2b(aV[ot][r]);
        __syncthreads();   // (10)
#pragma unroll
        for (int p = 0; p < 4; ++p) {
            const int idx = t + 256 * p;
            const int c = idx >> 3, n8 = (idx & 7) * 8;
            *(u16x8*)(vN + ((size_t)bt * CC + c) * NN + n0b + n8) =
                *(const u16x8*)&bufT[c * 72 + n8];
        }
    }
}

// one kx column of QK^T -> P' -> PV (per-wave private P; within-wave fence only)
__device__ __forceinline__ void kxstep(
    int i, int qx, size_t btNN, int bt, int l15, int g,
    const u16* __restrict__ kT, const u16* __restrict__ vN,
    const float* __restrict__ eexp, float dscale,
    const float (&qbk)[2], const u16x8 (&ql)[2][4],
    float (&ssum)[2], f32x4 (&o)[8][2], u16* P)
{
    const float invsq = 0.08838834764831843f;  // 1/sqrt(128)
    const int kxr = qx - 3 + i;
    const int kxc = min(max(kxr, 0), 31);
    const bool cval = (kxr == kxc);
    f32x4 acc[2][2];
#pragma unroll
    for (int mt = 0; mt < 2; ++mt)
#pragma unroll
        for (int nt = 0; nt < 2; ++nt) acc[mt][nt] = (f32x4){0.f, 0.f, 0.f, 0.f};
#pragma unroll
    for (int kk = 0; kk < 4; ++kk)
#pragma unroll
        for (int mt = 0; mt < 2; ++mt) {
            bf16x8 ka = *(const bf16x8*)(kT + (btNN + kxc * 32 + 16 * mt + l15) * CC + 32 * kk + 8 * g);
#pragma unroll
            for (int nt = 0; nt < 2; ++nt)
                acc[mt][nt] = __builtin_amdgcn_mfma_f32_16x16x32_bf16(
                    ka, __builtin_bit_cast(bf16x8, ql[nt][kk]), acc[mt][nt], 0, 0, 0);
        }
#pragma unroll
    for (int mt = 0; mt < 2; ++mt) {
        f32x4 ee4 = *(const f32x4*)(eexp + btNN + kxc * 32 + 16 * mt + 4 * g);
        f32x4 d4;
#pragma unroll
        for (int r = 0; r < 4; ++r) d4[r] = dscale * ee4[r];
#pragma unroll
        for (int nt = 0; nt < 2; ++nt) {
            const int qyv = l15 + 16 * nt;
            u16x4 pw;
#pragma unroll
            for (int r = 0; r < 4; ++r) {
                const float s = (d4[r] * acc[mt][nt][r] + qbk[nt]) * invsq;
                const int ky = 16 * mt + 4 * g + r;
                const int dy = ky - qyv;
                const bool vld = cval && (dy >= -3) && (dy <= 3);
                const float e = vld ? __expf(s) : 0.f;
                ssum[nt] += e;
                pw[r] = f2b(e * d4[r]);
            }
            *(u16x4*)&P[qyv * PSTs + 16 * mt + 4 * g] = pw;
        }
    }
    asm volatile("s_waitcnt lgkmcnt(0)" ::: "memory");
    __builtin_amdgcn_sched_barrier(0);
    bf16x8 pb[2];
#pragma unroll
    for (int nt = 0; nt < 2; ++nt)
        pb[nt] = *(const bf16x8*)&P[(16 * nt + l15) * PSTs + 8 * g];
#pragma unroll
    for (int mt = 0; mt < 8; ++mt) {
        bf16x8 va = *(const bf16x8*)(vN + ((size_t)bt * CC + 16 * mt + l15) * NN + kxc * 32 + 8 * g);
#pragma unroll
        for (int nt = 0; nt < 2; ++nt)
            o[mt][nt] = __builtin_amdgcn_mfma_f32_16x16x32_bf16(va, pb[nt], o[mt][nt], 0, 0, 0);
    }
}

// ---------- kernel 2: FUSED attention + conv + LIF, kx-split, LDS-staged Wf ----------
__global__ __launch_bounds__(512) void k_attnf(
    const u16* __restrict__ qT, const u16* __restrict__ kT,
    const u16* __restrict__ vN, const float* __restrict__ eexp,
    const float* __restrict__ partial,
    const float* __restrict__ bk, const float* __restrict__ bv,
    const u16* __restrict__ WfB, const float* __restrict__ bf,
    float* __restrict__ out)
{
    __shared__ u16 lds_u16[26624];   // region A (34816 B): P / o-scratch / att
    __shared__ float convq[4 * 32 * CQS];  // 18432 B
    __shared__ float sums_l[256];    // [w][nt][l15]
    __shared__ u16 wfbuf[16384];     // 32768 B — packed Wf
    const int t = threadIdx.x;
    const int id = blockIdx.x;
    const int b = id & 7, qx = id >> 3;   // XCD x owns b = x
    const int w = t >> 6, tt = w & 3, h = w >> 2;
    const int bt = b * 4 + tt;
    const int l = t & 63, l15 = l & 15, g = l >> 4;
    u16* att = lds_u16;                       // [4][32][CPA]
    float* scratch = (float*)lds_u16;         // [4][64][SQS] f32
    u16* P = lds_u16 + w * 32 * PSTs;         // 8 private buffers
    const size_t btNN = (size_t)bt * NN;

    // stage Wf (visible by the barriers before the conv phase)
#pragma unroll
    for (int p = 0; p < 4; ++p) {
        const int idx = t + 512 * p;
        *(u16x8*)(wfbuf + idx * 8) = *(const u16x8*)(WfB + idx * 8);
    }

    float S = 0.f;
    {
        const float* pp = partial + (size_t)bt * 16;
#pragma unroll
        for (int i = 0; i < 16; ++i) S += pp[i];
    }
    const float dscale = 1024.0f / S;

    u16x8 ql[2][4];
#pragma unroll
    for (int nt = 0; nt < 2; ++nt)
#pragma unroll
        for (int kk = 0; kk < 4; ++kk)
            ql[nt][kk] = *(const u16x8*)(qT + (btNN + qx * 32 + 16 * nt + l15) * CC + 32 * kk + 8 * g);

    float qbk[2] = {0.f, 0.f};
#pragma unroll
    for (int kk = 0; kk < 4; ++kk) {
        f32x4 b0 = *(const f32x4*)(bk + 32 * kk + 8 * g);
        f32x4 b1 = *(const f32x4*)(bk + 32 * kk + 8 * g + 4);
#pragma unroll
        for (int nt = 0; nt < 2; ++nt)
#pragma unroll
            for (int j = 0; j < 4; ++j) {
                qbk[nt] += b2f(ql[nt][kk][j]) * b0[j];
                qbk[nt] += b2f(ql[nt][kk][4 + j]) * b1[j];
            }
    }
#pragma unroll
    for (int nt = 0; nt < 2; ++nt) {
        qbk[nt] += __shfl_xor(qbk[nt], 16);
        qbk[nt] += __shfl_xor(qbk[nt], 32);
    }

    float ssum[2] = {0.f, 0.f};
    f32x4 o[8][2];
#pragma unroll
    for (int mt = 0; mt < 8; ++mt)
#pragma unroll
        for (int nt = 0; nt < 2; ++nt) o[mt][nt] = (f32x4){0.f, 0.f, 0.f, 0.f};

    if (h == 0) {
#pragma unroll
        for (int i = 0; i < 4; ++i)
            kxstep(i, qx, btNN, bt, l15, g, kT, vN, eexp, dscale, qbk, ql, ssum, o, P);
    } else {
#pragma unroll
        for (int i = 4; i < 7; ++i)
            kxstep(i, qx, btNN, bt, l15, g, kT, vN, eexp, dscale, qbk, ql, ssum, o, P);
    }
#pragma unroll
    for (int nt = 0; nt < 2; ++nt) {
        ssum[nt] += __shfl_xor(ssum[nt], 16);
        ssum[nt] += __shfl_xor(ssum[nt], 32);
        if (l < 16) sums_l[(w * 2 + nt) * 16 + l15] = ssum[nt];
    }
    __syncthreads();  // all P reads done; sums visible; region A reusable

#pragma unroll
    for (int c = 0; c < 2; ++c) {
        if (h == 1) {
#pragma unroll
            for (int m2 = 0; m2 < 4; ++m2)
#pragma unroll
                for (int nt = 0; nt < 2; ++nt)
#pragma unroll
                    for (int r = 0; r < 4; ++r)
                        scratch[tt * 64 * SQS + (16 * m2 + 4 * g + r) * SQS + 16 * nt + l15] =
                            o[4 * c + m2][nt][r];
        }
        __syncthreads();
        if (h == 0) {
#pragma unroll
            for (int m2 = 0; m2 < 4; ++m2)
#pragma unroll
                for (int nt = 0; nt < 2; ++nt)
#pragma unroll
                    for (int r = 0; r < 4; ++r)
                        o[4 * c + m2][nt][r] +=
                            scratch[tt * 64 * SQS + (16 * m2 + 4 * g + r) * SQS + 16 * nt + l15];
        }
        __syncthreads();
    }

    if (h == 0) {
        float inv[2];
#pragma unroll
        for (int nt = 0; nt < 2; ++nt)
            inv[nt] = 1.0f / (ssum[nt] + sums_l[((w + 4) * 2 + nt) * 16 + l15]);
        u16* attw = att + tt * 32 * CPA;
#pragma unroll
        for (int mt = 0; mt < 8; ++mt) {
            f32x4 bv4 = *(const f32x4*)(bv + 16 * mt + 4 * g);
#pragma unroll
            for (int nt = 0; nt < 2; ++nt) {
                u16x4 ov;
#pragma unroll
                for (int r = 0; r < 4; ++r) ov[r] = f2b(o[mt][nt][r] * inv[nt] + bv4[r]);
                *(u16x4*)&attw[(16 * nt + l15) * CPA + 16 * mt + 4 * g] = ov;
            }
        }
    }
    __syncthreads();  // att ready for both halves

    const u16* attw = att + tt * 32 * CPA;
    bf16x8 cb[4][2];
#pragma unroll
    for (int kk = 0; kk < 4; ++kk)
#pragma unroll
        for (int nt = 0; nt < 2; ++nt)
            cb[kk][nt] = *(const bf16x8*)&attw[(16 * nt + l15) * CPA + 32 * kk + 8 * g];

    const int cl = t >> 4, n2 = (t & 15) * 2;
#pragma unroll
    for (int cr = 0; cr < 4; ++cr) {
        const int ot = 2 * cr + h;
        f32x4 ca[2];
#pragma unroll
        for (int nt = 0; nt < 2; ++nt) ca[nt] = *(const f32x4*)(bf + 16 * ot + 4 * g);
#pragma unroll
        for (int kk = 0; kk < 4; ++kk) {
            bf16x8 afr = ldA(wfbuf, ot, kk, l);
#pragma unroll
            for (int nt = 0; nt < 2; ++nt)
                ca[nt] = __builtin_amdgcn_mfma_f32_16x16x32_bf16(afr, cb[kk][nt], ca[nt], 0, 0, 0);
        }
#pragma unroll
        for (int nt = 0; nt < 2; ++nt)
#pragma unroll
            for (int r = 0; r < 4; ++r)
                convq[tt * 32 * CQS + (16 * h + 4 * g + r) * CQS + 16 * nt + l15] = ca[nt][r];
        __syncthreads();
        float m0 = 0.f, m1 = 0.f;
#pragma unroll
        for (int tt2 = 0; tt2 < 4; ++tt2) {
            float2 x = *(const float2*)&convq[tt2 * 32 * CQS + cl * CQS + n2];
            m0 = m0 * 0.5f + x.x;
            m1 = m1 * 0.5f + x.y;
            float2 sp;
            sp.x = (m0 > 1.0f) ? 1.0f : 0.0f; if (m0 > 1.0f) m0 = 0.f;
            sp.y = (m1 > 1.0f) ? 1.0f : 0.0f; if (m1 > 1.0f) m1 = 0.f;
            *(float2*)(out + ((size_t)(b * 4 + tt2) * CC + 32 * cr + cl) * NN + qx * 32 + n2) = sp;
        }
        __syncthreads();
    }
}

extern "C" void kernel_launch(void* const* d_in, const int* in_sizes, int n_in,
                              void* d_out, int out_size, void* d_ws, size_t ws_size,
                              hipStream_t stream) {
    (void)in_sizes; (void)n_in; (void)out_size; (void)ws_size;
    const float* edge = (const float*)d_in[0];
    const float* dvs  = (const float*)d_in[1];
    const float* We = (const float*)d_in[2];
    const float* be = (const float*)d_in[3];
    const float* Wd = (const float*)d_in[4];
    const float* bd = (const float*)d_in[5];
    const float* Wq = (const float*)d_in[6];
    const float* bq = (const float*)d_in[7];
    const float* Wk = (const float*)d_in[8];
    const float* bk = (const float*)d_in[9];
    const float* Wv = (const float*)d_in[10];
    const float* bv = (const float*)d_in[11];
    const float* Wf = (const float*)d_in[12];
    const float* bf = (const float*)d_in[13];
    float* out = (float*)d_out;

    const size_t S = (size_t)BTOT * NN * CC;  // 4.19M elems
    u16* qT   = (u16*)d_ws;
    u16* kT   = qT + S;
    u16* vN   = kT + S;
    u16* WbAll = vN + S;                      // 6 * 16384 u16
    float* fbase = (float*)(WbAll + 6 * 16384);
    float* cvec  = fbase;                     // 3 * 128
    float* eexp  = cvec + 3 * CC;             // BTOT*NN
    float* partial = eexp + BTOT * NN;        // BTOT*16
    u16* WeB  = WbAll + 0 * 16384;
    u16* WdB  = WbAll + 1 * 16384;
    u16* WqeB = WbAll + 2 * 16384;
    u16* WkdB = WbAll + 3 * 16384;
    u16* WvdB = WbAll + 4 * 16384;
    u16* WfB  = WbAll + 5 * 16384;
    float* cq = cvec;
    float* ck = cvec + CC;
    float* cv = cvec + 2 * CC;

    k_prep<<<216, 256, 0, stream>>>(We, Wd, Wf, Wq, Wk, Wv, be, bd, WbAll, cvec);
    k_front<<<512, 256, 0, stream>>>(edge, dvs, WeB, WdB, WqeB, WkdB, WvdB,
                                     be, bd, bq, cq, ck, cv, eexp, partial, qT, kT, vN);
    k_attnf<<<256, 512, 0, stream>>>(qT, kT, vN, eexp, partial, bk, bv, WfB, bf, out);
}